// Round 6
// baseline (473.803 us; speedup 1.0000x reference)
//
#include <hip/hip_runtime.h>
#include <cstdint>

#define N_NODES 50000
#define N_EDGES 800000
#define EP (N_EDGES + N_NODES)   // edges + self-loops
#define IN_DIM 32
#define HID 64
#define HEADS 4
#define HC 256                   // HID*HEADS
#define OUT_DIM 128
#define NEG_SLOPE 0.2f
#define LN_EPS 1e-5f
#define SCAN_B 1024
#define NB ((N_NODES + SCAN_B - 1) / SCAN_B)   // 49

typedef __attribute__((ext_vector_type(8))) short bf16x8;
typedef __attribute__((ext_vector_type(16))) float f32x16;

__device__ __forceinline__ unsigned bf16rne(float f) {
    unsigned u = __float_as_uint(f);
    return (u + 0x7fffu + ((u >> 16) & 1u)) >> 16;
}
__device__ __forceinline__ unsigned pack_bf2(float a, float b) {
    return bf16rne(a) | (bf16rne(b) << 16);
}
__device__ __forceinline__ float bf_lo(unsigned w) { return __uint_as_float(w << 16); }
__device__ __forceinline__ float bf_hi(unsigned w) { return __uint_as_float(w & 0xffff0000u); }

// ------- input projection + ELU: h = elu(x @ W_in + b_in), bf16 out -------
__global__ void k_in_proj(const float* __restrict__ x, const float* __restrict__ W,
                          const float* __restrict__ b, unsigned short* __restrict__ out) {
    int g = blockIdx.x * blockDim.x + threadIdx.x;   // N*HID threads, exact
    int n = g >> 6, j = g & 63;
    const float* xr = x + n * IN_DIM;
    float acc = b[j];
#pragma unroll
    for (int k = 0; k < IN_DIM; ++k) acc += xr[k] * W[k * HID + j];
    acc = acc > 0.f ? acc : (__expf(acc) - 1.f);
    out[g] = (unsigned short)bf16rne(acc);
}

// ------- pack the three weight matrices to bf16 [K/8][N][8] -------
__global__ void k_wpack(const float* __restrict__ w0, const float* __restrict__ w1,
                        const float* __restrict__ w2, unsigned short* __restrict__ p0,
                        unsigned short* __restrict__ p1, unsigned short* __restrict__ p2) {
    int g = blockIdx.x * blockDim.x + threadIdx.x;
    if (g < HID * HC) {                      // lin0_w: 64x256
        int k = g >> 8, n = g & 255;
        p0[(((k >> 3) * HC) + n) * 8 + (k & 7)] = (unsigned short)bf16rne(w0[g]);
    } else if (g < HID * HC + HC * HC) {     // lin1_w: 256x256
        int t = g - HID * HC;
        int k = t >> 8, n = t & 255;
        p1[(((k >> 3) * HC) + n) * 8 + (k & 7)] = (unsigned short)bf16rne(w1[t]);
    } else if (g < HID * HC + HC * HC + HC * OUT_DIM) {   // W_out: 256x128
        int t = g - HID * HC - HC * HC;
        int k = t >> 7, n = t & 127;
        p2[(((k >> 3) * OUT_DIM) + n) * 8 + (k & 7)] = (unsigned short)bf16rne(w2[t]);
    }
}

// ======= MFMA GEMM + fused attention dots =======
// hh[M,256] = A[M,K] @ B[K,256]; a_src[n,h]=<hh[n,h,:],att_s[h,:]> from f32 acc
template <int K>
__global__ __launch_bounds__(256) void k_gemm_lin(
        const unsigned short* __restrict__ A, const unsigned short* __restrict__ Bp,
        const float* __restrict__ att_s, const float* __restrict__ att_d,
        unsigned short* __restrict__ hh, float* __restrict__ a_src,
        float* __restrict__ a_dst) {
    const int lane = threadIdx.x & 63;
    const int quad = lane >> 5, c = lane & 31;
    const int m0 = blockIdx.x * 128 + (threadIdx.x >> 6) * 32;
    f32x16 acc[8];
#pragma unroll
    for (int nt = 0; nt < 8; ++nt)
#pragma unroll
        for (int i = 0; i < 16; ++i) acc[nt][i] = 0.f;
    int mrow = m0 + c; if (mrow >= N_NODES) mrow = N_NODES - 1;
    const size_t abase = (size_t)mrow * K + quad * 8;
    for (int k0 = 0; k0 < K; k0 += 16) {
        bf16x8 af = *(const bf16x8*)(A + abase + k0);
        const unsigned short* bk = Bp + ((size_t)(k0 >> 3) + quad) * (HC * 8);
#pragma unroll
        for (int nt = 0; nt < 8; ++nt) {
            bf16x8 bf = *(const bf16x8*)(bk + (nt * 32 + c) * 8);
            acc[nt] = __builtin_amdgcn_mfma_f32_32x32x16_bf16(af, bf, acc[nt], 0, 0, 0);
        }
    }
    // att vectors for this lane's columns (flat index col = nt*32+c = h*64+cc)
    float asv[8], adv[8];
#pragma unroll
    for (int nt = 0; nt < 8; ++nt) {
        int col = nt * 32 + c;
        asv[nt] = att_s[col];
        adv[nt] = att_d[col];
    }
#pragma unroll
    for (int reg = 0; reg < 16; ++reg) {
        int row = (reg & 3) + 8 * (reg >> 2) + 4 * quad;
        int m = m0 + row;
        bool valid = (m < N_NODES);
        if (valid) {
            size_t base = (size_t)m * HC + c;
#pragma unroll
            for (int nt = 0; nt < 8; ++nt)
                hh[base + nt * 32] = (unsigned short)bf16rne(acc[nt][reg]);
        }
        // per-head dots (head h covers nt tiles 2h, 2h+1); reduce over 32 lanes of quad
#pragma unroll
        for (int h = 0; h < 4; ++h) {
            float rs = acc[2 * h][reg] * asv[2 * h] + acc[2 * h + 1][reg] * asv[2 * h + 1];
            float rd = acc[2 * h][reg] * adv[2 * h] + acc[2 * h + 1][reg] * adv[2 * h + 1];
#pragma unroll
            for (int mk = 1; mk < 32; mk <<= 1) {
                rs += __shfl_xor(rs, mk, 64);
                rd += __shfl_xor(rd, mk, 64);
            }
            if (c == 0 && valid) {
                a_src[m * HEADS + h] = rs;
                a_dst[m * HEADS + h] = rd;
            }
        }
    }
}

// ================= CSR build (dst-sorted edge list) =================
__global__ void k_hist(const int* __restrict__ ei, int* __restrict__ counts) {
    int e = blockIdx.x * blockDim.x + threadIdx.x;
    if (e >= EP) return;
    int d = (e < N_EDGES) ? ei[N_EDGES + e] : (e - N_EDGES);
    atomicAdd(&counts[d], 1);
}

__global__ void k_scan1(const int* __restrict__ counts, int* __restrict__ chunk_excl,
                        int* __restrict__ bsum) {
    __shared__ int buf[SCAN_B];
    int i = blockIdx.x * SCAN_B + threadIdx.x;
    int v = (i < N_NODES) ? counts[i] : 0;
    buf[threadIdx.x] = v;
    __syncthreads();
    for (int off = 1; off < SCAN_B; off <<= 1) {
        int t = (threadIdx.x >= off) ? buf[threadIdx.x - off] : 0;
        __syncthreads();
        buf[threadIdx.x] += t;
        __syncthreads();
    }
    if (i < N_NODES) chunk_excl[i] = buf[threadIdx.x] - v;
    if (threadIdx.x == SCAN_B - 1) bsum[blockIdx.x] = buf[SCAN_B - 1];
}

// scan3 with fused block-sum prefix (first wave shuffle-sums bsum[0..blockIdx))
__global__ void k_scan3(const int* __restrict__ chunk_excl, const int* __restrict__ bsum,
                        int* __restrict__ row_ptr, int* __restrict__ cursor) {
    __shared__ int sbase;
    if (threadIdx.x < 64) {
        int v = (threadIdx.x < blockIdx.x) ? bsum[threadIdx.x] : 0;   // NB=49 <= 64
#pragma unroll
        for (int mk = 1; mk < 64; mk <<= 1) v += __shfl_xor(v, mk, 64);
        if (threadIdx.x == 0) sbase = v;
    }
    __syncthreads();
    int i = blockIdx.x * SCAN_B + threadIdx.x;
    if (i < N_NODES) {
        int v = chunk_excl[i] + sbase;
        row_ptr[i] = v;
        cursor[i] = v;
    }
    if (i == 0) row_ptr[N_NODES] = EP;
}

__global__ void k_scatter(const int* __restrict__ ei, int* __restrict__ cursor,
                          int* __restrict__ esrc) {
    int e = blockIdx.x * blockDim.x + threadIdx.x;
    if (e >= EP) return;
    int s, d;
    if (e < N_EDGES) { s = ei[e]; d = ei[N_EDGES + e]; } else { s = d = e - N_EDGES; }
    int pos = atomicAdd(&cursor[d], 1);
    esrc[pos] = s;
}

// ===== fused GAT aggregate: one wave per dst node, 4-edge unrolled gather =====
__global__ __launch_bounds__(256) void k_gat_agg(
        const int* __restrict__ row_ptr, const int* __restrict__ esrc,
        const unsigned short* __restrict__ hh, const float* __restrict__ a_src,
        const float* __restrict__ a_dst, const float* __restrict__ bias,
        unsigned short* __restrict__ out) {
    const int wave = threadIdx.x >> 6;
    const int lane = threadIdx.x & 63;
    const int d = blockIdx.x * 4 + wave;          // 50000 = 12500*4, exact
    const int h = lane >> 4;
    const int j = lane * 4;
    const float ad = a_dst[d * HEADS + h];
    const int beg = row_ptr[d], end = row_ptr[d + 1];
    float4 acc = {0.f, 0.f, 0.f, 0.f};
    float psum = 0.f;
    for (int base = beg; base < end; base += 64) {
        int cnt = end - base; if (cnt > 64) cnt = 64;
        int idx = base + lane;
        int myv = esrc[idx < end ? idx : end - 1];
        int i = 0;
        for (; i + 4 <= cnt; i += 4) {
            int s0 = __shfl(myv, i, 64);
            int s1 = __shfl(myv, i + 1, 64);
            int s2 = __shfl(myv, i + 2, 64);
            int s3 = __shfl(myv, i + 3, 64);
            float as0 = a_src[s0 * HEADS + h];
            float as1 = a_src[s1 * HEADS + h];
            float as2 = a_src[s2 * HEADS + h];
            float as3 = a_src[s3 * HEADS + h];
            uint2 g0 = *(const uint2*)(hh + (size_t)s0 * HC + j);
            uint2 g1 = *(const uint2*)(hh + (size_t)s1 * HC + j);
            uint2 g2 = *(const uint2*)(hh + (size_t)s2 * HC + j);
            uint2 g3 = *(const uint2*)(hh + (size_t)s3 * HC + j);
            float e0 = as0 + ad; e0 = e0 > 0.f ? e0 : NEG_SLOPE * e0;
            float e1 = as1 + ad; e1 = e1 > 0.f ? e1 : NEG_SLOPE * e1;
            float e2 = as2 + ad; e2 = e2 > 0.f ? e2 : NEG_SLOPE * e2;
            float e3 = as3 + ad; e3 = e3 > 0.f ? e3 : NEG_SLOPE * e3;
            float p0 = __expf(e0), p1 = __expf(e1), p2 = __expf(e2), p3 = __expf(e3);
            psum += (p0 + p1) + (p2 + p3);
            acc.x += p0 * bf_lo(g0.x) + p1 * bf_lo(g1.x) + p2 * bf_lo(g2.x) + p3 * bf_lo(g3.x);
            acc.y += p0 * bf_hi(g0.x) + p1 * bf_hi(g1.x) + p2 * bf_hi(g2.x) + p3 * bf_hi(g3.x);
            acc.z += p0 * bf_lo(g0.y) + p1 * bf_lo(g1.y) + p2 * bf_lo(g2.y) + p3 * bf_lo(g3.y);
            acc.w += p0 * bf_hi(g0.y) + p1 * bf_hi(g1.y) + p2 * bf_hi(g2.y) + p3 * bf_hi(g3.y);
        }
        for (; i < cnt; ++i) {
            int s0 = __shfl(myv, i, 64);
            float as0 = a_src[s0 * HEADS + h];
            uint2 g0 = *(const uint2*)(hh + (size_t)s0 * HC + j);
            float e0 = as0 + ad; e0 = e0 > 0.f ? e0 : NEG_SLOPE * e0;
            float p0 = __expf(e0);
            psum += p0;
            acc.x += p0 * bf_lo(g0.x);
            acc.y += p0 * bf_hi(g0.x);
            acc.z += p0 * bf_lo(g0.y);
            acc.w += p0 * bf_hi(g0.y);
        }
    }
    const float inv = 1.f / (psum + 1e-16f);
    const float4 bb = *(const float4*)(bias + j);
    float4 v;
    v.x = acc.x * inv + bb.x; v.y = acc.y * inv + bb.y;
    v.z = acc.z * inv + bb.z; v.w = acc.w * inv + bb.w;
    v.x = v.x > 0.f ? v.x : (__expf(v.x) - 1.f);
    v.y = v.y > 0.f ? v.y : (__expf(v.y) - 1.f);
    v.z = v.z > 0.f ? v.z : (__expf(v.z) - 1.f);
    v.w = v.w > 0.f ? v.w : (__expf(v.w) - 1.f);
    uint2 pk;
    pk.x = pack_bf2(v.x, v.y);
    pk.y = pack_bf2(v.z, v.w);
    *(uint2*)(out + (size_t)d * HC + j) = pk;
}

// ======= MFMA out-proj + fused LayerNorm: out[M,128] = A[M,256] @ B -> LN =======
__global__ __launch_bounds__(256) void k_gemm_out(
        const unsigned short* __restrict__ A, const unsigned short* __restrict__ Bp,
        const float* __restrict__ b, const float* __restrict__ gamma,
        const float* __restrict__ beta, float* __restrict__ out) {
    const int lane = threadIdx.x & 63;
    const int quad = lane >> 5, c = lane & 31;
    const int m0 = blockIdx.x * 128 + (threadIdx.x >> 6) * 32;
    f32x16 acc[4];
#pragma unroll
    for (int nt = 0; nt < 4; ++nt)
#pragma unroll
        for (int i = 0; i < 16; ++i) acc[nt][i] = 0.f;
    int mrow = m0 + c; if (mrow >= N_NODES) mrow = N_NODES - 1;
    const size_t abase = (size_t)mrow * HC + quad * 8;
    for (int k0 = 0; k0 < HC; k0 += 16) {
        bf16x8 af = *(const bf16x8*)(A + abase + k0);
        const unsigned short* bk = Bp + ((size_t)(k0 >> 3) + quad) * (OUT_DIM * 8);
#pragma unroll
        for (int nt = 0; nt < 4; ++nt) {
            bf16x8 bf = *(const bf16x8*)(bk + (nt * 32 + c) * 8);
            acc[nt] = __builtin_amdgcn_mfma_f32_32x32x16_bf16(af, bf, acc[nt], 0, 0, 0);
        }
    }
    float bb[4], gg[4], be[4];
#pragma unroll
    for (int nt = 0; nt < 4; ++nt) {
        int col = nt * 32 + c;
        bb[nt] = b[col]; gg[nt] = gamma[col]; be[nt] = beta[col];
    }
#pragma unroll
    for (int reg = 0; reg < 16; ++reg) {
        int row = (reg & 3) + 8 * (reg >> 2) + 4 * quad;
        int m = m0 + row;
        float v[4];
        float s = 0.f, s2 = 0.f;
#pragma unroll
        for (int nt = 0; nt < 4; ++nt) {
            v[nt] = acc[nt][reg] + bb[nt];
            s += v[nt]; s2 += v[nt] * v[nt];
        }
#pragma unroll
        for (int mk = 1; mk < 32; mk <<= 1) {
            s += __shfl_xor(s, mk, 64);
            s2 += __shfl_xor(s2, mk, 64);
        }
        float mu = s * (1.f / OUT_DIM);
        float var = s2 * (1.f / OUT_DIM) - mu * mu;
        float inv = rsqrtf(var + LN_EPS);
        if (m < N_NODES) {
            size_t base = (size_t)m * OUT_DIM + c;
#pragma unroll
            for (int nt = 0; nt < 4; ++nt)
                out[base + nt * 32] = (v[nt] - mu) * inv * gg[nt] + be[nt];
        }
    }
}

extern "C" void kernel_launch(void* const* d_in, const int* in_sizes, int n_in,
                              void* d_out, int out_size, void* d_ws, size_t ws_size,
                              hipStream_t stream) {
    const float* x        = (const float*)d_in[0];
    const int*   ei       = (const int*)  d_in[1];
    const float* W_in     = (const float*)d_in[2];
    const float* b_in     = (const float*)d_in[3];
    const float* lin0_w   = (const float*)d_in[4];
    const float* att0_src = (const float*)d_in[5];
    const float* att0_dst = (const float*)d_in[6];
    const float* bias0    = (const float*)d_in[7];
    const float* lin1_w   = (const float*)d_in[8];
    const float* att1_src = (const float*)d_in[9];
    const float* att1_dst = (const float*)d_in[10];
    const float* bias1    = (const float*)d_in[11];
    const float* W_out    = (const float*)d_in[12];
    const float* b_out    = (const float*)d_in[13];
    const float* ln_gamma = (const float*)d_in[14];
    const float* ln_beta  = (const float*)d_in[15];
    float* out = (float*)d_out;

    unsigned short* us = (unsigned short*)d_ws;
    unsigned short* h_in_bf = us;                                  // N*HID
    unsigned short* hh_bf   = h_in_bf + (size_t)N_NODES * HID;     // N*HC
    unsigned short* feat_bf = hh_bf + (size_t)N_NODES * HC;        // N*HC
    unsigned short* p0      = feat_bf + (size_t)N_NODES * HC;      // 64*256
    unsigned short* p1      = p0 + HID * HC;                       // 256*256
    unsigned short* p2      = p1 + HC * HC;                        // 256*128
    float* a_src = (float*)(p2 + HC * OUT_DIM);
    float* a_dst = a_src + (size_t)N_NODES * HEADS;
    int* counts     = (int*)(a_dst + (size_t)N_NODES * HEADS);
    int* chunk_excl = counts + N_NODES;
    int* bsum       = chunk_excl + N_NODES;
    int* row_ptr    = bsum + NB;
    int* cursor     = row_ptr + N_NODES + 1;
    int* esrc       = cursor + N_NODES;

    // 1. input projection (bf16 out) + weight packing
    k_in_proj<<<(N_NODES * HID) / 256, 256, 0, stream>>>(x, W_in, b_in, h_in_bf);
    k_wpack<<<(HID * HC + HC * HC + HC * OUT_DIM + 255) / 256, 256, 0, stream>>>(
        lin0_w, lin1_w, W_out, p0, p1, p2);

    // 2. CSR build (once; shared by both GAT layers)
    hipMemsetAsync(counts, 0, N_NODES * sizeof(int), stream);
    k_hist<<<(EP + 255) / 256, 256, 0, stream>>>(ei, counts);
    k_scan1<<<NB, SCAN_B, 0, stream>>>(counts, chunk_excl, bsum);
    k_scan3<<<NB, SCAN_B, 0, stream>>>(chunk_excl, bsum, row_ptr, cursor);
    k_scatter<<<(EP + 255) / 256, 256, 0, stream>>>(ei, cursor, esrc);

    const int gemm_grid = (N_NODES + 127) / 128;   // 391

    // ---- GAT layer 0 ----
    k_gemm_lin<HID><<<gemm_grid, 256, 0, stream>>>(h_in_bf, p0, att0_src, att0_dst,
                                                   hh_bf, a_src, a_dst);
    k_gat_agg<<<N_NODES / 4, 256, 0, stream>>>(row_ptr, esrc, hh_bf, a_src, a_dst,
                                               bias0, feat_bf);

    // ---- GAT layer 1 ----
    k_gemm_lin<HC><<<gemm_grid, 256, 0, stream>>>(feat_bf, p1, att1_src, att1_dst,
                                                  hh_bf, a_src, a_dst);
    k_gat_agg<<<N_NODES / 4, 256, 0, stream>>>(row_ptr, esrc, hh_bf, a_src, a_dst,
                                               bias1, feat_bf);

    // ---- output projection + LayerNorm ----
    k_gemm_out<<<gemm_grid, 256, 0, stream>>>(feat_bf, p2, b_out, ln_gamma, ln_beta, out);
}

// Round 7
// 411.754 us; speedup vs baseline: 1.1507x; 1.1507x over previous
//
#include <hip/hip_runtime.h>
#include <cstdint>

#define N_NODES 50000
#define N_EDGES 800000
#define EP (N_EDGES + N_NODES)   // edges + self-loops
#define IN_DIM 32
#define HID 64
#define HEADS 4
#define HC 256                   // HID*HEADS
#define OUT_DIM 128
#define NEG_SLOPE 0.2f
#define LN_EPS 1e-5f
#define SCAN_B 1024
#define NB ((N_NODES + SCAN_B - 1) / SCAN_B)   // 49

typedef __attribute__((ext_vector_type(8))) short bf16x8;
typedef __attribute__((ext_vector_type(16))) float f32x16;

__device__ __forceinline__ unsigned bf16rne(float f) {
    unsigned u = __float_as_uint(f);
    return (u + 0x7fffu + ((u >> 16) & 1u)) >> 16;
}
__device__ __forceinline__ unsigned pack_bf2(float a, float b) {
    return bf16rne(a) | (bf16rne(b) << 16);
}
__device__ __forceinline__ float bf_lo(unsigned w) { return __uint_as_float(w << 16); }
__device__ __forceinline__ float bf_hi(unsigned w) { return __uint_as_float(w & 0xffff0000u); }

// ------- input projection + ELU: h = elu(x @ W_in + b_in), bf16 out -------
__global__ void k_in_proj(const float* __restrict__ x, const float* __restrict__ W,
                          const float* __restrict__ b, unsigned short* __restrict__ out) {
    int g = blockIdx.x * blockDim.x + threadIdx.x;   // N*HID threads, exact
    int n = g >> 6, j = g & 63;
    const float* xr = x + n * IN_DIM;
    float acc = b[j];
#pragma unroll
    for (int k = 0; k < IN_DIM; ++k) acc += xr[k] * W[k * HID + j];
    acc = acc > 0.f ? acc : (__expf(acc) - 1.f);
    out[g] = (unsigned short)bf16rne(acc);
}

// ------- pack the three weight matrices to bf16 [K/8][N][8] -------
__global__ void k_wpack(const float* __restrict__ w0, const float* __restrict__ w1,
                        const float* __restrict__ w2, unsigned short* __restrict__ p0,
                        unsigned short* __restrict__ p1, unsigned short* __restrict__ p2) {
    int g = blockIdx.x * blockDim.x + threadIdx.x;
    if (g < HID * HC) {                      // lin0_w: 64x256
        int k = g >> 8, n = g & 255;
        p0[(((k >> 3) * HC) + n) * 8 + (k & 7)] = (unsigned short)bf16rne(w0[g]);
    } else if (g < HID * HC + HC * HC) {     // lin1_w: 256x256
        int t = g - HID * HC;
        int k = t >> 8, n = t & 255;
        p1[(((k >> 3) * HC) + n) * 8 + (k & 7)] = (unsigned short)bf16rne(w1[t]);
    } else if (g < HID * HC + HC * HC + HC * OUT_DIM) {   // W_out: 256x128
        int t = g - HID * HC - HC * HC;
        int k = t >> 7, n = t & 127;
        p2[(((k >> 3) * OUT_DIM) + n) * 8 + (k & 7)] = (unsigned short)bf16rne(w2[t]);
    }
}

// ======= MFMA GEMM: hh[M,256] = A[M,K] @ B[K,256] (bf16 in/out) =======
// wave = 32 rows x 128 cols (acc[4], 64 VGPR) for occupancy; block = 64 rows.
template <int K>
__global__ __launch_bounds__(256) void k_gemm_lin(
        const unsigned short* __restrict__ A, const unsigned short* __restrict__ Bp,
        unsigned short* __restrict__ hh) {
    const int lane = threadIdx.x & 63;
    const int quad = lane >> 5, c = lane & 31;
    const int wave = threadIdx.x >> 6;
    const int m0 = blockIdx.x * 64 + (wave >> 1) * 32;
    const int cb = (wave & 1) * 128;         // column half
    f32x16 acc[4];
#pragma unroll
    for (int nt = 0; nt < 4; ++nt)
#pragma unroll
        for (int i = 0; i < 16; ++i) acc[nt][i] = 0.f;
    int mrow = m0 + c; if (mrow >= N_NODES) mrow = N_NODES - 1;
    const size_t abase = (size_t)mrow * K + quad * 8;
    for (int k0 = 0; k0 < K; k0 += 16) {
        bf16x8 af = *(const bf16x8*)(A + abase + k0);
        const unsigned short* bk = Bp + ((size_t)(k0 >> 3) + quad) * (HC * 8);
#pragma unroll
        for (int nt = 0; nt < 4; ++nt) {
            bf16x8 bf = *(const bf16x8*)(bk + (cb + nt * 32 + c) * 8);
            acc[nt] = __builtin_amdgcn_mfma_f32_32x32x16_bf16(af, bf, acc[nt], 0, 0, 0);
        }
    }
#pragma unroll
    for (int reg = 0; reg < 16; ++reg) {
        int row = (reg & 3) + 8 * (reg >> 2) + 4 * quad;
        int m = m0 + row;
        if (m < N_NODES) {
            size_t base = (size_t)m * HC + cb + c;
#pragma unroll
            for (int nt = 0; nt < 4; ++nt)
                hh[base + nt * 32] = (unsigned short)bf16rne(acc[nt][reg]);
        }
    }
}

// ------- attention dots from bf16 hh: a_src[n,h]=<hh[n,h,:],att_s[h,:]> -------
// wave handles 2 nodes (32 lanes/node, 8 cols/lane)
__global__ void k_att_dots(const unsigned short* __restrict__ hh,
                           const float* __restrict__ att_s, const float* __restrict__ att_d,
                           float* __restrict__ a_src, float* __restrict__ a_dst) {
    int wid = (blockIdx.x * blockDim.x + threadIdx.x) >> 6;
    int lane = threadIdx.x & 63;
    int node = wid * 2 + (lane >> 5);          // 50000 even: exact
    int c0 = (lane & 31) * 8;
    int h = (lane & 31) >> 3;                  // head = c0/64
    uint4 raw = *(const uint4*)(hh + (size_t)node * HC + c0);
    float as = 0.f, ad = 0.f;
#pragma unroll
    for (int t = 0; t < 4; ++t) {
        unsigned w = ((const unsigned*)&raw)[t];
        float v0 = __uint_as_float(w << 16);
        float v1 = __uint_as_float(w & 0xffff0000u);
        int cc = (c0 & 63) + t * 2;
        as += v0 * att_s[h * HID + cc] + v1 * att_s[h * HID + cc + 1];
        ad += v0 * att_d[h * HID + cc] + v1 * att_d[h * HID + cc + 1];
    }
#pragma unroll
    for (int m = 1; m < 8; m <<= 1) {
        as += __shfl_xor(as, m, 64);
        ad += __shfl_xor(ad, m, 64);
    }
    if ((lane & 7) == 0) {
        a_src[node * HEADS + h] = as;
        a_dst[node * HEADS + h] = ad;
    }
}

// ================= CSR build (dst-sorted edge list) =================
__global__ void k_hist(const int* __restrict__ ei, int* __restrict__ counts) {
    int e = blockIdx.x * blockDim.x + threadIdx.x;
    if (e >= EP) return;
    int d = (e < N_EDGES) ? ei[N_EDGES + e] : (e - N_EDGES);
    atomicAdd(&counts[d], 1);
}

__global__ void k_scan1(const int* __restrict__ counts, int* __restrict__ chunk_excl,
                        int* __restrict__ bsum) {
    __shared__ int buf[SCAN_B];
    int i = blockIdx.x * SCAN_B + threadIdx.x;
    int v = (i < N_NODES) ? counts[i] : 0;
    buf[threadIdx.x] = v;
    __syncthreads();
    for (int off = 1; off < SCAN_B; off <<= 1) {
        int t = (threadIdx.x >= off) ? buf[threadIdx.x - off] : 0;
        __syncthreads();
        buf[threadIdx.x] += t;
        __syncthreads();
    }
    if (i < N_NODES) chunk_excl[i] = buf[threadIdx.x] - v;
    if (threadIdx.x == SCAN_B - 1) bsum[blockIdx.x] = buf[SCAN_B - 1];
}

// scan3 with fused block-sum prefix (first wave shuffle-sums bsum[0..blockIdx))
__global__ void k_scan3(const int* __restrict__ chunk_excl, const int* __restrict__ bsum,
                        int* __restrict__ row_ptr, int* __restrict__ cursor) {
    __shared__ int sbase;
    if (threadIdx.x < 64) {
        int v = (threadIdx.x < blockIdx.x) ? bsum[threadIdx.x] : 0;   // NB=49 <= 64
#pragma unroll
        for (int mk = 1; mk < 64; mk <<= 1) v += __shfl_xor(v, mk, 64);
        if (threadIdx.x == 0) sbase = v;
    }
    __syncthreads();
    int i = blockIdx.x * SCAN_B + threadIdx.x;
    if (i < N_NODES) {
        int v = chunk_excl[i] + sbase;
        row_ptr[i] = v;
        cursor[i] = v;
    }
    if (i == 0) row_ptr[N_NODES] = EP;
}

__global__ void k_scatter(const int* __restrict__ ei, int* __restrict__ cursor,
                          int* __restrict__ esrc) {
    int e = blockIdx.x * blockDim.x + threadIdx.x;
    if (e >= EP) return;
    int s, d;
    if (e < N_EDGES) { s = ei[e]; d = ei[N_EDGES + e]; } else { s = d = e - N_EDGES; }
    int pos = atomicAdd(&cursor[d], 1);
    esrc[pos] = s;
}

// ===== fused GAT aggregate: one wave per dst node, 4-edge unrolled gather =====
__global__ __launch_bounds__(256) void k_gat_agg(
        const int* __restrict__ row_ptr, const int* __restrict__ esrc,
        const unsigned short* __restrict__ hh, const float* __restrict__ a_src,
        const float* __restrict__ a_dst, const float* __restrict__ bias,
        unsigned short* __restrict__ out) {
    const int wave = threadIdx.x >> 6;
    const int lane = threadIdx.x & 63;
    const int d = blockIdx.x * 4 + wave;          // 50000 = 12500*4, exact
    const int h = lane >> 4;
    const int j = lane * 4;
    const float ad = a_dst[d * HEADS + h];
    const int beg = row_ptr[d], end = row_ptr[d + 1];
    float4 acc = {0.f, 0.f, 0.f, 0.f};
    float psum = 0.f;
    for (int base = beg; base < end; base += 64) {
        int cnt = end - base; if (cnt > 64) cnt = 64;
        int idx = base + lane;
        int myv = esrc[idx < end ? idx : end - 1];
        int i = 0;
        for (; i + 4 <= cnt; i += 4) {
            int s0 = __shfl(myv, i, 64);
            int s1 = __shfl(myv, i + 1, 64);
            int s2 = __shfl(myv, i + 2, 64);
            int s3 = __shfl(myv, i + 3, 64);
            float as0 = a_src[s0 * HEADS + h];
            float as1 = a_src[s1 * HEADS + h];
            float as2 = a_src[s2 * HEADS + h];
            float as3 = a_src[s3 * HEADS + h];
            uint2 g0 = *(const uint2*)(hh + (size_t)s0 * HC + j);
            uint2 g1 = *(const uint2*)(hh + (size_t)s1 * HC + j);
            uint2 g2 = *(const uint2*)(hh + (size_t)s2 * HC + j);
            uint2 g3 = *(const uint2*)(hh + (size_t)s3 * HC + j);
            float e0 = as0 + ad; e0 = e0 > 0.f ? e0 : NEG_SLOPE * e0;
            float e1 = as1 + ad; e1 = e1 > 0.f ? e1 : NEG_SLOPE * e1;
            float e2 = as2 + ad; e2 = e2 > 0.f ? e2 : NEG_SLOPE * e2;
            float e3 = as3 + ad; e3 = e3 > 0.f ? e3 : NEG_SLOPE * e3;
            float p0 = __expf(e0), p1 = __expf(e1), p2 = __expf(e2), p3 = __expf(e3);
            psum += (p0 + p1) + (p2 + p3);
            acc.x += p0 * bf_lo(g0.x) + p1 * bf_lo(g1.x) + p2 * bf_lo(g2.x) + p3 * bf_lo(g3.x);
            acc.y += p0 * bf_hi(g0.x) + p1 * bf_hi(g1.x) + p2 * bf_hi(g2.x) + p3 * bf_hi(g3.x);
            acc.z += p0 * bf_lo(g0.y) + p1 * bf_lo(g1.y) + p2 * bf_lo(g2.y) + p3 * bf_lo(g3.y);
            acc.w += p0 * bf_hi(g0.y) + p1 * bf_hi(g1.y) + p2 * bf_hi(g2.y) + p3 * bf_hi(g3.y);
        }
        for (; i < cnt; ++i) {
            int s0 = __shfl(myv, i, 64);
            float as0 = a_src[s0 * HEADS + h];
            uint2 g0 = *(const uint2*)(hh + (size_t)s0 * HC + j);
            float e0 = as0 + ad; e0 = e0 > 0.f ? e0 : NEG_SLOPE * e0;
            float p0 = __expf(e0);
            psum += p0;
            acc.x += p0 * bf_lo(g0.x);
            acc.y += p0 * bf_hi(g0.x);
            acc.z += p0 * bf_lo(g0.y);
            acc.w += p0 * bf_hi(g0.y);
        }
    }
    const float inv = 1.f / (psum + 1e-16f);
    const float4 bb = *(const float4*)(bias + j);
    float4 v;
    v.x = acc.x * inv + bb.x; v.y = acc.y * inv + bb.y;
    v.z = acc.z * inv + bb.z; v.w = acc.w * inv + bb.w;
    v.x = v.x > 0.f ? v.x : (__expf(v.x) - 1.f);
    v.y = v.y > 0.f ? v.y : (__expf(v.y) - 1.f);
    v.z = v.z > 0.f ? v.z : (__expf(v.z) - 1.f);
    v.w = v.w > 0.f ? v.w : (__expf(v.w) - 1.f);
    uint2 pk;
    pk.x = pack_bf2(v.x, v.y);
    pk.y = pack_bf2(v.z, v.w);
    *(uint2*)(out + (size_t)d * HC + j) = pk;
}

// ======= MFMA out-proj + fused LayerNorm: out[M,128] = A[M,256] @ B -> LN =======
__global__ __launch_bounds__(256) void k_gemm_out(
        const unsigned short* __restrict__ A, const unsigned short* __restrict__ Bp,
        const float* __restrict__ b, const float* __restrict__ gamma,
        const float* __restrict__ beta, float* __restrict__ out) {
    const int lane = threadIdx.x & 63;
    const int quad = lane >> 5, c = lane & 31;
    const int m0 = blockIdx.x * 128 + (threadIdx.x >> 6) * 32;
    f32x16 acc[4];
#pragma unroll
    for (int nt = 0; nt < 4; ++nt)
#pragma unroll
        for (int i = 0; i < 16; ++i) acc[nt][i] = 0.f;
    int mrow = m0 + c; if (mrow >= N_NODES) mrow = N_NODES - 1;
    const size_t abase = (size_t)mrow * HC + quad * 8;
    for (int k0 = 0; k0 < HC; k0 += 16) {
        bf16x8 af = *(const bf16x8*)(A + abase + k0);
        const unsigned short* bk = Bp + ((size_t)(k0 >> 3) + quad) * (OUT_DIM * 8);
#pragma unroll
        for (int nt = 0; nt < 4; ++nt) {
            bf16x8 bf = *(const bf16x8*)(bk + (nt * 32 + c) * 8);
            acc[nt] = __builtin_amdgcn_mfma_f32_32x32x16_bf16(af, bf, acc[nt], 0, 0, 0);
        }
    }
    float bb[4], gg[4], be[4];
#pragma unroll
    for (int nt = 0; nt < 4; ++nt) {
        int col = nt * 32 + c;
        bb[nt] = b[col]; gg[nt] = gamma[col]; be[nt] = beta[col];
    }
#pragma unroll
    for (int reg = 0; reg < 16; ++reg) {
        int row = (reg & 3) + 8 * (reg >> 2) + 4 * quad;
        int m = m0 + row;
        float v[4];
        float s = 0.f, s2 = 0.f;
#pragma unroll
        for (int nt = 0; nt < 4; ++nt) {
            v[nt] = acc[nt][reg] + bb[nt];
            s += v[nt]; s2 += v[nt] * v[nt];
        }
#pragma unroll
        for (int mk = 1; mk < 32; mk <<= 1) {
            s += __shfl_xor(s, mk, 64);
            s2 += __shfl_xor(s2, mk, 64);
        }
        float mu = s * (1.f / OUT_DIM);
        float var = s2 * (1.f / OUT_DIM) - mu * mu;
        float inv = rsqrtf(var + LN_EPS);
        if (m < N_NODES) {
            size_t base = (size_t)m * OUT_DIM + c;
#pragma unroll
            for (int nt = 0; nt < 4; ++nt)
                out[base + nt * 32] = (v[nt] - mu) * inv * gg[nt] + be[nt];
        }
    }
}

extern "C" void kernel_launch(void* const* d_in, const int* in_sizes, int n_in,
                              void* d_out, int out_size, void* d_ws, size_t ws_size,
                              hipStream_t stream) {
    const float* x        = (const float*)d_in[0];
    const int*   ei       = (const int*)  d_in[1];
    const float* W_in     = (const float*)d_in[2];
    const float* b_in     = (const float*)d_in[3];
    const float* lin0_w   = (const float*)d_in[4];
    const float* att0_src = (const float*)d_in[5];
    const float* att0_dst = (const float*)d_in[6];
    const float* bias0    = (const float*)d_in[7];
    const float* lin1_w   = (const float*)d_in[8];
    const float* att1_src = (const float*)d_in[9];
    const float* att1_dst = (const float*)d_in[10];
    const float* bias1    = (const float*)d_in[11];
    const float* W_out    = (const float*)d_in[12];
    const float* b_out    = (const float*)d_in[13];
    const float* ln_gamma = (const float*)d_in[14];
    const float* ln_beta  = (const float*)d_in[15];
    float* out = (float*)d_out;

    unsigned short* us = (unsigned short*)d_ws;
    unsigned short* h_in_bf = us;                                  // N*HID
    unsigned short* hh_bf   = h_in_bf + (size_t)N_NODES * HID;     // N*HC
    unsigned short* feat_bf = hh_bf + (size_t)N_NODES * HC;        // N*HC
    unsigned short* p0      = feat_bf + (size_t)N_NODES * HC;      // 64*256
    unsigned short* p1      = p0 + HID * HC;                       // 256*256
    unsigned short* p2      = p1 + HC * HC;                        // 256*128
    float* a_src = (float*)(p2 + HC * OUT_DIM);
    float* a_dst = a_src + (size_t)N_NODES * HEADS;
    int* counts     = (int*)(a_dst + (size_t)N_NODES * HEADS);
    int* chunk_excl = counts + N_NODES;
    int* bsum       = chunk_excl + N_NODES;
    int* row_ptr    = bsum + NB;
    int* cursor     = row_ptr + N_NODES + 1;
    int* esrc       = cursor + N_NODES;

    // 1. input projection (bf16 out) + weight packing
    k_in_proj<<<(N_NODES * HID) / 256, 256, 0, stream>>>(x, W_in, b_in, h_in_bf);
    k_wpack<<<(HID * HC + HC * HC + HC * OUT_DIM + 255) / 256, 256, 0, stream>>>(
        lin0_w, lin1_w, W_out, p0, p1, p2);

    // 2. CSR build (once; shared by both GAT layers)
    hipMemsetAsync(counts, 0, N_NODES * sizeof(int), stream);
    k_hist<<<(EP + 255) / 256, 256, 0, stream>>>(ei, counts);
    k_scan1<<<NB, SCAN_B, 0, stream>>>(counts, chunk_excl, bsum);
    k_scan3<<<NB, SCAN_B, 0, stream>>>(chunk_excl, bsum, row_ptr, cursor);
    k_scatter<<<(EP + 255) / 256, 256, 0, stream>>>(ei, cursor, esrc);

    const int lin_grid = (N_NODES + 63) / 64;      // 782
    const int out_grid = (N_NODES + 127) / 128;    // 391
    const int dots_grid = N_NODES / 8;             // 6250

    // ---- GAT layer 0 ----
    k_gemm_lin<HID><<<lin_grid, 256, 0, stream>>>(h_in_bf, p0, hh_bf);
    k_att_dots<<<dots_grid, 256, 0, stream>>>(hh_bf, att0_src, att0_dst, a_src, a_dst);
    k_gat_agg<<<N_NODES / 4, 256, 0, stream>>>(row_ptr, esrc, hh_bf, a_src, a_dst,
                                               bias0, feat_bf);

    // ---- GAT layer 1 ----
    k_gemm_lin<HC><<<lin_grid, 256, 0, stream>>>(feat_bf, p1, hh_bf);
    k_att_dots<<<dots_grid, 256, 0, stream>>>(hh_bf, att1_src, att1_dst, a_src, a_dst);
    k_gat_agg<<<N_NODES / 4, 256, 0, stream>>>(row_ptr, esrc, hh_bf, a_src, a_dst,
                                               bias1, feat_bf);

    // ---- output projection + LayerNorm ----
    k_gemm_out<<<out_grid, 256, 0, stream>>>(feat_bf, p2, b_out, ln_gamma, ln_beta, out);
}

// Round 8
// 377.340 us; speedup vs baseline: 1.2556x; 1.0912x over previous
//
#include <hip/hip_runtime.h>
#include <cstdint>

#define N_NODES 50000
#define N_EDGES 800000
#define EP (N_EDGES + N_NODES)   // edges + self-loops
#define IN_DIM 32
#define HID 64
#define HEADS 4
#define HC 256                   // HID*HEADS
#define OUT_DIM 128
#define NEG_SLOPE 0.2f
#define LN_EPS 1e-5f
#define SCAN_B 1024
#define NB ((N_NODES + SCAN_B - 1) / SCAN_B)   // 49

typedef __attribute__((ext_vector_type(8))) short bf16x8;
typedef __attribute__((ext_vector_type(16))) float f32x16;

__device__ __forceinline__ unsigned bf16rne(float f) {
    unsigned u = __float_as_uint(f);
    return (u + 0x7fffu + ((u >> 16) & 1u)) >> 16;
}
__device__ __forceinline__ unsigned pack_bf2(float a, float b) {
    return bf16rne(a) | (bf16rne(b) << 16);
}
__device__ __forceinline__ float bf_lo(unsigned w) { return __uint_as_float(w << 16); }
__device__ __forceinline__ float bf_hi(unsigned w) { return __uint_as_float(w & 0xffff0000u); }

// ------- input projection + ELU: h = elu(x @ W_in + b_in), bf16 out -------
__global__ void k_in_proj(const float* __restrict__ x, const float* __restrict__ W,
                          const float* __restrict__ b, unsigned short* __restrict__ out) {
    int g = blockIdx.x * blockDim.x + threadIdx.x;   // N*HID threads, exact
    int n = g >> 6, j = g & 63;
    const float* xr = x + n * IN_DIM;
    float acc = b[j];
#pragma unroll
    for (int k = 0; k < IN_DIM; ++k) acc += xr[k] * W[k * HID + j];
    acc = acc > 0.f ? acc : (__expf(acc) - 1.f);
    out[g] = (unsigned short)bf16rne(acc);
}

// ------- pack the three weight matrices to bf16 [K/8][N][8] -------
__global__ void k_wpack(const float* __restrict__ w0, const float* __restrict__ w1,
                        const float* __restrict__ w2, unsigned short* __restrict__ p0,
                        unsigned short* __restrict__ p1, unsigned short* __restrict__ p2) {
    int g = blockIdx.x * blockDim.x + threadIdx.x;
    if (g < HID * HC) {                      // lin0_w: 64x256
        int k = g >> 8, n = g & 255;
        p0[(((k >> 3) * HC) + n) * 8 + (k & 7)] = (unsigned short)bf16rne(w0[g]);
    } else if (g < HID * HC + HC * HC) {     // lin1_w: 256x256
        int t = g - HID * HC;
        int k = t >> 8, n = t & 255;
        p1[(((k >> 3) * HC) + n) * 8 + (k & 7)] = (unsigned short)bf16rne(w1[t]);
    } else if (g < HID * HC + HC * HC + HC * OUT_DIM) {   // W_out: 256x128
        int t = g - HID * HC - HC * HC;
        int k = t >> 7, n = t & 127;
        p2[(((k >> 3) * OUT_DIM) + n) * 8 + (k & 7)] = (unsigned short)bf16rne(w2[t]);
    }
}

// ------- combined attention weight columns: w_as[k,h] = <W[k, h*64:], att_s[h,:]> -------
// packed as extra B-tile [K/8][32][8] (cols 0-3 = src heads, 4-7 = dst heads, rest 0)
__global__ void k_att_w(const float* __restrict__ w, const float* __restrict__ as,
                        const float* __restrict__ ad, unsigned short* __restrict__ ext,
                        int K) {
    int t = blockIdx.x * blockDim.x + threadIdx.x;   // K*8 threads
    if (t >= K * 8) return;
    int k = t >> 3, col = t & 7, h = col & 3;
    const float* att = (col < 4) ? as : ad;
    float acc = 0.f;
#pragma unroll 4
    for (int c = 0; c < HID; ++c) acc += w[k * HC + h * HID + c] * att[h * HID + c];
    ext[(k >> 3) * 256 + col * 8 + (k & 7)] = (unsigned short)bf16rne(acc);
}

// ======= MFMA GEMM: hh[M,256] = A[M,K] @ B[K,256]; odd waves also compute =======
// ======= the 8 attention-dot columns (extra B-tile) -> a_src/a_dst directly =====
template <int K>
__global__ __launch_bounds__(256) void k_gemm_lin(
        const unsigned short* __restrict__ A, const unsigned short* __restrict__ Bp,
        const unsigned short* __restrict__ Ext, unsigned short* __restrict__ hh,
        float* __restrict__ a_src, float* __restrict__ a_dst) {
    const int lane = threadIdx.x & 63;
    const int quad = lane >> 5, c = lane & 31;
    const int wave = threadIdx.x >> 6;
    const int m0 = blockIdx.x * 64 + (wave >> 1) * 32;
    const int cb = (wave & 1) * 128;         // column half
    f32x16 acc[4];
#pragma unroll
    for (int nt = 0; nt < 4; ++nt)
#pragma unroll
        for (int i = 0; i < 16; ++i) acc[nt][i] = 0.f;
    f32x16 acce;
#pragma unroll
    for (int i = 0; i < 16; ++i) acce[i] = 0.f;
    int mrow = m0 + c; if (mrow >= N_NODES) mrow = N_NODES - 1;
    const size_t abase = (size_t)mrow * K + quad * 8;
    for (int k0 = 0; k0 < K; k0 += 16) {
        bf16x8 af = *(const bf16x8*)(A + abase + k0);
        const unsigned short* bk = Bp + ((size_t)(k0 >> 3) + quad) * (HC * 8);
#pragma unroll
        for (int nt = 0; nt < 4; ++nt) {
            bf16x8 bf = *(const bf16x8*)(bk + (cb + nt * 32 + c) * 8);
            acc[nt] = __builtin_amdgcn_mfma_f32_32x32x16_bf16(af, bf, acc[nt], 0, 0, 0);
        }
        if (wave & 1) {
            bf16x8 bfe = *(const bf16x8*)(Ext + ((k0 >> 3) + quad) * 256 + c * 8);
            acce = __builtin_amdgcn_mfma_f32_32x32x16_bf16(af, bfe, acce, 0, 0, 0);
        }
    }
#pragma unroll
    for (int reg = 0; reg < 16; ++reg) {
        int row = (reg & 3) + 8 * (reg >> 2) + 4 * quad;
        int m = m0 + row;
        if (m < N_NODES) {
            size_t base = (size_t)m * HC + cb + c;
#pragma unroll
            for (int nt = 0; nt < 4; ++nt)
                hh[base + nt * 32] = (unsigned short)bf16rne(acc[nt][reg]);
            if ((wave & 1) && c < 8) {
                float v = acce[reg];
                if (c < 4) a_src[m * HEADS + c] = v;
                else       a_dst[m * HEADS + (c - 4)] = v;
            }
        }
    }
}

// ================= CSR build (dst-sorted edge list) =================
// hist also records each edge's arrival rank (atomicAdd return) -> scatter is atomic-free
__global__ void k_hist(const int* __restrict__ ei, int* __restrict__ counts,
                       int* __restrict__ rank) {
    int e = blockIdx.x * blockDim.x + threadIdx.x;
    if (e >= EP) return;
    int d = (e < N_EDGES) ? ei[N_EDGES + e] : (e - N_EDGES);
    rank[e] = atomicAdd(&counts[d], 1);
}

__global__ void k_scan1(const int* __restrict__ counts, int* __restrict__ chunk_excl,
                        int* __restrict__ bsum) {
    __shared__ int buf[SCAN_B];
    int i = blockIdx.x * SCAN_B + threadIdx.x;
    int v = (i < N_NODES) ? counts[i] : 0;
    buf[threadIdx.x] = v;
    __syncthreads();
    for (int off = 1; off < SCAN_B; off <<= 1) {
        int t = (threadIdx.x >= off) ? buf[threadIdx.x - off] : 0;
        __syncthreads();
        buf[threadIdx.x] += t;
        __syncthreads();
    }
    if (i < N_NODES) chunk_excl[i] = buf[threadIdx.x] - v;
    if (threadIdx.x == SCAN_B - 1) bsum[blockIdx.x] = buf[SCAN_B - 1];
}

// scan3 with fused block-sum prefix (first wave shuffle-sums bsum[0..blockIdx))
__global__ void k_scan3(const int* __restrict__ chunk_excl, const int* __restrict__ bsum,
                        int* __restrict__ row_ptr) {
    __shared__ int sbase;
    if (threadIdx.x < 64) {
        int v = (threadIdx.x < blockIdx.x) ? bsum[threadIdx.x] : 0;   // NB=49 <= 64
#pragma unroll
        for (int mk = 1; mk < 64; mk <<= 1) v += __shfl_xor(v, mk, 64);
        if (threadIdx.x == 0) sbase = v;
    }
    __syncthreads();
    int i = blockIdx.x * SCAN_B + threadIdx.x;
    if (i < N_NODES) row_ptr[i] = chunk_excl[i] + sbase;
    if (i == 0) row_ptr[N_NODES] = EP;
}

__global__ void k_scatter(const int* __restrict__ ei, const int* __restrict__ row_ptr,
                          const int* __restrict__ rank, int* __restrict__ esrc) {
    int e = blockIdx.x * blockDim.x + threadIdx.x;
    if (e >= EP) return;
    int s, d;
    if (e < N_EDGES) { s = ei[e]; d = ei[N_EDGES + e]; } else { s = d = e - N_EDGES; }
    esrc[row_ptr[d] + rank[e]] = s;
}

// ===== fused GAT aggregate: one wave per dst node, 8-edge unrolled gather =====
__global__ __launch_bounds__(256) void k_gat_agg(
        const int* __restrict__ row_ptr, const int* __restrict__ esrc,
        const unsigned short* __restrict__ hh, const float* __restrict__ a_src,
        const float* __restrict__ a_dst, const float* __restrict__ bias,
        unsigned short* __restrict__ out) {
    const int wave = threadIdx.x >> 6;
    const int lane = threadIdx.x & 63;
    const int d = blockIdx.x * 4 + wave;          // 50000 = 12500*4, exact
    const int h = lane >> 4;
    const unsigned j = (unsigned)(lane * 4);
    const float ad = a_dst[((unsigned)d << 2) + h];
    const int beg = row_ptr[d], end = row_ptr[d + 1];
    float4 acc = {0.f, 0.f, 0.f, 0.f};
    float psum = 0.f;
    for (int base = beg; base < end; base += 64) {
        int cnt = end - base; if (cnt > 64) cnt = 64;
        int idx = base + lane;
        int myv = esrc[idx < end ? idx : end - 1];
        int i = 0;
        for (; i + 8 <= cnt; i += 8) {
            int s0 = __shfl(myv, i, 64),     s1 = __shfl(myv, i + 1, 64);
            int s2 = __shfl(myv, i + 2, 64), s3 = __shfl(myv, i + 3, 64);
            int s4 = __shfl(myv, i + 4, 64), s5 = __shfl(myv, i + 5, 64);
            int s6 = __shfl(myv, i + 6, 64), s7 = __shfl(myv, i + 7, 64);
            float as0 = a_src[((unsigned)s0 << 2) + h], as1 = a_src[((unsigned)s1 << 2) + h];
            float as2 = a_src[((unsigned)s2 << 2) + h], as3 = a_src[((unsigned)s3 << 2) + h];
            float as4 = a_src[((unsigned)s4 << 2) + h], as5 = a_src[((unsigned)s5 << 2) + h];
            float as6 = a_src[((unsigned)s6 << 2) + h], as7 = a_src[((unsigned)s7 << 2) + h];
            uint2 g0 = *(const uint2*)(hh + (((unsigned)s0 << 8) + j));
            uint2 g1 = *(const uint2*)(hh + (((unsigned)s1 << 8) + j));
            uint2 g2 = *(const uint2*)(hh + (((unsigned)s2 << 8) + j));
            uint2 g3 = *(const uint2*)(hh + (((unsigned)s3 << 8) + j));
            uint2 g4 = *(const uint2*)(hh + (((unsigned)s4 << 8) + j));
            uint2 g5 = *(const uint2*)(hh + (((unsigned)s5 << 8) + j));
            uint2 g6 = *(const uint2*)(hh + (((unsigned)s6 << 8) + j));
            uint2 g7 = *(const uint2*)(hh + (((unsigned)s7 << 8) + j));
            float e0 = as0 + ad, e1 = as1 + ad, e2 = as2 + ad, e3 = as3 + ad;
            float e4 = as4 + ad, e5 = as5 + ad, e6 = as6 + ad, e7 = as7 + ad;
            e0 = fmaxf(e0, NEG_SLOPE * e0); e1 = fmaxf(e1, NEG_SLOPE * e1);
            e2 = fmaxf(e2, NEG_SLOPE * e2); e3 = fmaxf(e3, NEG_SLOPE * e3);
            e4 = fmaxf(e4, NEG_SLOPE * e4); e5 = fmaxf(e5, NEG_SLOPE * e5);
            e6 = fmaxf(e6, NEG_SLOPE * e6); e7 = fmaxf(e7, NEG_SLOPE * e7);
            float p0 = __expf(e0), p1 = __expf(e1), p2 = __expf(e2), p3 = __expf(e3);
            float p4 = __expf(e4), p5 = __expf(e5), p6 = __expf(e6), p7 = __expf(e7);
            psum += ((p0 + p1) + (p2 + p3)) + ((p4 + p5) + (p6 + p7));
            acc.x += p0 * bf_lo(g0.x) + p1 * bf_lo(g1.x) + p2 * bf_lo(g2.x) + p3 * bf_lo(g3.x)
                   + p4 * bf_lo(g4.x) + p5 * bf_lo(g5.x) + p6 * bf_lo(g6.x) + p7 * bf_lo(g7.x);
            acc.y += p0 * bf_hi(g0.x) + p1 * bf_hi(g1.x) + p2 * bf_hi(g2.x) + p3 * bf_hi(g3.x)
                   + p4 * bf_hi(g4.x) + p5 * bf_hi(g5.x) + p6 * bf_hi(g6.x) + p7 * bf_hi(g7.x);
            acc.z += p0 * bf_lo(g0.y) + p1 * bf_lo(g1.y) + p2 * bf_lo(g2.y) + p3 * bf_lo(g3.y)
                   + p4 * bf_lo(g4.y) + p5 * bf_lo(g5.y) + p6 * bf_lo(g6.y) + p7 * bf_lo(g7.y);
            acc.w += p0 * bf_hi(g0.y) + p1 * bf_hi(g1.y) + p2 * bf_hi(g2.y) + p3 * bf_hi(g3.y)
                   + p4 * bf_hi(g4.y) + p5 * bf_hi(g5.y) + p6 * bf_hi(g6.y) + p7 * bf_hi(g7.y);
        }
        for (; i < cnt; ++i) {
            int s0 = __shfl(myv, i, 64);
            float as0 = a_src[((unsigned)s0 << 2) + h];
            uint2 g0 = *(const uint2*)(hh + (((unsigned)s0 << 8) + j));
            float e0 = as0 + ad;
            e0 = fmaxf(e0, NEG_SLOPE * e0);
            float p0 = __expf(e0);
            psum += p0;
            acc.x += p0 * bf_lo(g0.x);
            acc.y += p0 * bf_hi(g0.x);
            acc.z += p0 * bf_lo(g0.y);
            acc.w += p0 * bf_hi(g0.y);
        }
    }
    const float inv = 1.f / (psum + 1e-16f);
    const float4 bb = *(const float4*)(bias + j);
    float4 v;
    v.x = acc.x * inv + bb.x; v.y = acc.y * inv + bb.y;
    v.z = acc.z * inv + bb.z; v.w = acc.w * inv + bb.w;
    v.x = v.x > 0.f ? v.x : (__expf(v.x) - 1.f);
    v.y = v.y > 0.f ? v.y : (__expf(v.y) - 1.f);
    v.z = v.z > 0.f ? v.z : (__expf(v.z) - 1.f);
    v.w = v.w > 0.f ? v.w : (__expf(v.w) - 1.f);
    uint2 pk;
    pk.x = pack_bf2(v.x, v.y);
    pk.y = pack_bf2(v.z, v.w);
    *(uint2*)(out + (size_t)d * HC + j) = pk;
}

// ======= MFMA out-proj + fused LayerNorm: out[M,128] = A[M,256] @ B -> LN =======
__global__ __launch_bounds__(256) void k_gemm_out(
        const unsigned short* __restrict__ A, const unsigned short* __restrict__ Bp,
        const float* __restrict__ b, const float* __restrict__ gamma,
        const float* __restrict__ beta, float* __restrict__ out) {
    const int lane = threadIdx.x & 63;
    const int quad = lane >> 5, c = lane & 31;
    const int m0 = blockIdx.x * 128 + (threadIdx.x >> 6) * 32;
    f32x16 acc[4];
#pragma unroll
    for (int nt = 0; nt < 4; ++nt)
#pragma unroll
        for (int i = 0; i < 16; ++i) acc[nt][i] = 0.f;
    int mrow = m0 + c; if (mrow >= N_NODES) mrow = N_NODES - 1;
    const size_t abase = (size_t)mrow * HC + quad * 8;
    for (int k0 = 0; k0 < HC; k0 += 16) {
        bf16x8 af = *(const bf16x8*)(A + abase + k0);
        const unsigned short* bk = Bp + ((size_t)(k0 >> 3) + quad) * (OUT_DIM * 8);
#pragma unroll
        for (int nt = 0; nt < 4; ++nt) {
            bf16x8 bf = *(const bf16x8*)(bk + (nt * 32 + c) * 8);
            acc[nt] = __builtin_amdgcn_mfma_f32_32x32x16_bf16(af, bf, acc[nt], 0, 0, 0);
        }
    }
    float bb[4], gg[4], be[4];
#pragma unroll
    for (int nt = 0; nt < 4; ++nt) {
        int col = nt * 32 + c;
        bb[nt] = b[col]; gg[nt] = gamma[col]; be[nt] = beta[col];
    }
#pragma unroll
    for (int reg = 0; reg < 16; ++reg) {
        int row = (reg & 3) + 8 * (reg >> 2) + 4 * quad;
        int m = m0 + row;
        float v[4];
        float s = 0.f, s2 = 0.f;
#pragma unroll
        for (int nt = 0; nt < 4; ++nt) {
            v[nt] = acc[nt][reg] + bb[nt];
            s += v[nt]; s2 += v[nt] * v[nt];
        }
#pragma unroll
        for (int mk = 1; mk < 32; mk <<= 1) {
            s += __shfl_xor(s, mk, 64);
            s2 += __shfl_xor(s2, mk, 64);
        }
        float mu = s * (1.f / OUT_DIM);
        float var = s2 * (1.f / OUT_DIM) - mu * mu;
        float inv = rsqrtf(var + LN_EPS);
        if (m < N_NODES) {
            size_t base = (size_t)m * OUT_DIM + c;
#pragma unroll
            for (int nt = 0; nt < 4; ++nt)
                out[base + nt * 32] = (v[nt] - mu) * inv * gg[nt] + be[nt];
        }
    }
}

extern "C" void kernel_launch(void* const* d_in, const int* in_sizes, int n_in,
                              void* d_out, int out_size, void* d_ws, size_t ws_size,
                              hipStream_t stream) {
    const float* x        = (const float*)d_in[0];
    const int*   ei       = (const int*)  d_in[1];
    const float* W_in     = (const float*)d_in[2];
    const float* b_in     = (const float*)d_in[3];
    const float* lin0_w   = (const float*)d_in[4];
    const float* att0_src = (const float*)d_in[5];
    const float* att0_dst = (const float*)d_in[6];
    const float* bias0    = (const float*)d_in[7];
    const float* lin1_w   = (const float*)d_in[8];
    const float* att1_src = (const float*)d_in[9];
    const float* att1_dst = (const float*)d_in[10];
    const float* bias1    = (const float*)d_in[11];
    const float* W_out    = (const float*)d_in[12];
    const float* b_out    = (const float*)d_in[13];
    const float* ln_gamma = (const float*)d_in[14];
    const float* ln_beta  = (const float*)d_in[15];
    float* out = (float*)d_out;

    unsigned short* us = (unsigned short*)d_ws;
    unsigned short* h_in_bf = us;                                  // N*HID
    unsigned short* hh_bf   = h_in_bf + (size_t)N_NODES * HID;     // N*HC
    unsigned short* feat_bf = hh_bf + (size_t)N_NODES * HC;        // N*HC
    unsigned short* p0      = feat_bf + (size_t)N_NODES * HC;      // 64*256
    unsigned short* p1      = p0 + HID * HC;                       // 256*256
    unsigned short* p2      = p1 + HC * HC;                        // 256*128
    unsigned short* ext0    = p2 + HC * OUT_DIM;                   // (64/8)*32*8 = 2048
    unsigned short* ext1    = ext0 + 2048;                         // (256/8)*32*8 = 8192
    float* a_src = (float*)(ext1 + 8192);
    float* a_dst = a_src + (size_t)N_NODES * HEADS;
    int* counts     = (int*)(a_dst + (size_t)N_NODES * HEADS);
    int* chunk_excl = counts + N_NODES;
    int* bsum       = chunk_excl + N_NODES;
    int* row_ptr    = bsum + NB;
    int* rank       = row_ptr + N_NODES + 1;       // EP
    int* esrc       = rank + EP;                   // EP

    // 1. input projection (bf16 out) + weight packing + combined att columns
    k_in_proj<<<(N_NODES * HID) / 256, 256, 0, stream>>>(x, W_in, b_in, h_in_bf);
    k_wpack<<<(HID * HC + HC * HC + HC * OUT_DIM + 255) / 256, 256, 0, stream>>>(
        lin0_w, lin1_w, W_out, p0, p1, p2);
    hipMemsetAsync(ext0, 0, (2048 + 8192) * sizeof(unsigned short), stream);
    k_att_w<<<(HID * 8 + 255) / 256, 256, 0, stream>>>(lin0_w, att0_src, att0_dst, ext0, HID);
    k_att_w<<<(HC * 8 + 255) / 256, 256, 0, stream>>>(lin1_w, att1_src, att1_dst, ext1, HC);

    // 2. CSR build (once; shared by both GAT layers)
    hipMemsetAsync(counts, 0, N_NODES * sizeof(int), stream);
    k_hist<<<(EP + 255) / 256, 256, 0, stream>>>(ei, counts, rank);
    k_scan1<<<NB, SCAN_B, 0, stream>>>(counts, chunk_excl, bsum);
    k_scan3<<<NB, SCAN_B, 0, stream>>>(chunk_excl, bsum, row_ptr);
    k_scatter<<<(EP + 255) / 256, 256, 0, stream>>>(ei, row_ptr, rank, esrc);

    const int lin_grid = (N_NODES + 63) / 64;      // 782
    const int out_grid = (N_NODES + 127) / 128;    // 391

    // ---- GAT layer 0 ----
    k_gemm_lin<HID><<<lin_grid, 256, 0, stream>>>(h_in_bf, p0, ext0, hh_bf, a_src, a_dst);
    k_gat_agg<<<N_NODES / 4, 256, 0, stream>>>(row_ptr, esrc, hh_bf, a_src, a_dst,
                                               bias0, feat_bf);

    // ---- GAT layer 1 ----
    k_gemm_lin<HC><<<lin_grid, 256, 0, stream>>>(feat_bf, p1, ext1, hh_bf, a_src, a_dst);
    k_gat_agg<<<N_NODES / 4, 256, 0, stream>>>(row_ptr, esrc, hh_bf, a_src, a_dst,
                                               bias1, feat_bf);

    // ---- output projection + LayerNorm ----
    k_gemm_out<<<out_grid, 256, 0, stream>>>(feat_bf, p2, b_out, ln_gamma, ln_beta, out);
}

// Round 9
// 364.967 us; speedup vs baseline: 1.2982x; 1.0339x over previous
//
#include <hip/hip_runtime.h>
#include <cstdint>

#define N_NODES 50000
#define N_EDGES 800000
#define EP (N_EDGES + N_NODES)   // edges + self-loops
#define IN_DIM 32
#define HID 64
#define HEADS 4
#define HC 256                   // HID*HEADS
#define OUT_DIM 128
#define NEG_SLOPE 0.2f
#define LN_EPS 1e-5f
#define SCAN_B 1024
#define NB ((N_NODES + SCAN_B - 1) / SCAN_B)   // 49

typedef __attribute__((ext_vector_type(8))) short bf16x8;
typedef __attribute__((ext_vector_type(16))) float f32x16;

__device__ __forceinline__ unsigned bf16rne(float f) {
    unsigned u = __float_as_uint(f);
    return (u + 0x7fffu + ((u >> 16) & 1u)) >> 16;
}
__device__ __forceinline__ unsigned pack_bf2(float a, float b) {
    return bf16rne(a) | (bf16rne(b) << 16);
}
__device__ __forceinline__ float bf_lo(unsigned w) { return __uint_as_float(w << 16); }
// hi half used raw: low 16 bits are sub-ulp noise (< 1 bf16 ulp), skip the AND
__device__ __forceinline__ float bf_hi_raw(unsigned w) { return __uint_as_float(w); }

// ===== fused prep: input proj (blocks 0..12499) | weight pack (448) | ext (40) =====
#define PREP_INPROJ ((N_NODES * HID) / 256)                    // 12500
#define PREP_WPACK ((HID * HC + HC * HC + HC * OUT_DIM) / 256) // 448
#define PREP_EXT 40                                            // 2048+8192 elems
__global__ void k_prep(const float* __restrict__ x, const float* __restrict__ W_in,
                       const float* __restrict__ b_in, unsigned short* __restrict__ h_in,
                       const float* __restrict__ w0, const float* __restrict__ w1,
                       const float* __restrict__ w2, unsigned short* __restrict__ p0,
                       unsigned short* __restrict__ p1, unsigned short* __restrict__ p2,
                       const float* __restrict__ as0, const float* __restrict__ ad0,
                       unsigned short* __restrict__ ext0,
                       const float* __restrict__ as1, const float* __restrict__ ad1,
                       unsigned short* __restrict__ ext1) {
    if (blockIdx.x < PREP_INPROJ) {
        int g = blockIdx.x * 256 + threadIdx.x;
        int n = g >> 6, j = g & 63;
        const float* xr = x + n * IN_DIM;
        float acc = b_in[j];
#pragma unroll
        for (int k = 0; k < IN_DIM; ++k) acc += xr[k] * W_in[k * HID + j];
        acc = acc > 0.f ? acc : (__expf(acc) - 1.f);
        h_in[g] = (unsigned short)bf16rne(acc);
    } else if (blockIdx.x < PREP_INPROJ + PREP_WPACK) {
        int g = (blockIdx.x - PREP_INPROJ) * 256 + threadIdx.x;
        if (g < HID * HC) {                      // lin0_w: 64x256
            int k = g >> 8, n = g & 255;
            p0[(((k >> 3) * HC) + n) * 8 + (k & 7)] = (unsigned short)bf16rne(w0[g]);
        } else if (g < HID * HC + HC * HC) {     // lin1_w: 256x256
            int t = g - HID * HC;
            int k = t >> 8, n = t & 255;
            p1[(((k >> 3) * HC) + n) * 8 + (k & 7)] = (unsigned short)bf16rne(w1[t]);
        } else {                                 // W_out: 256x128
            int t = g - HID * HC - HC * HC;
            int k = t >> 7, n = t & 127;
            p2[(((k >> 3) * OUT_DIM) + n) * 8 + (k & 7)] = (unsigned short)bf16rne(w2[t]);
        }
    } else {
        int t = (blockIdx.x - PREP_INPROJ - PREP_WPACK) * 256 + threadIdx.x;
        const float* w; const float* as; const float* ad; unsigned short* ext; int e;
        if (t < 2048) { w = w0; as = as0; ad = ad0; ext = ext0; e = t; }
        else if (t < 2048 + 8192) { w = w1; as = as1; ad = ad1; ext = ext1; e = t - 2048; }
        else return;
        int kb = e >> 8, rem = e & 255, col = rem >> 3, kk = rem & 7;
        int k = kb * 8 + kk;
        float acc = 0.f;
        if (col < 8) {
            int h = col & 3;
            const float* att = (col < 4) ? as : ad;
#pragma unroll 4
            for (int c = 0; c < HID; ++c) acc += w[k * HC + h * HID + c] * att[h * HID + c];
        }
        ext[e] = (unsigned short)bf16rne(acc);
    }
}

// ======= MFMA GEMM: hh[M,256] = A[M,K] @ B[K,256]; odd waves also compute =======
// ======= the 8 attention-dot columns (extra B-tile) -> a_src/a_dst directly =====
template <int K>
__global__ __launch_bounds__(256) void k_gemm_lin(
        const unsigned short* __restrict__ A, const unsigned short* __restrict__ Bp,
        const unsigned short* __restrict__ Ext, unsigned short* __restrict__ hh,
        float* __restrict__ a_src, float* __restrict__ a_dst) {
    const int lane = threadIdx.x & 63;
    const int quad = lane >> 5, c = lane & 31;
    const int wave = threadIdx.x >> 6;
    const int m0 = blockIdx.x * 64 + (wave >> 1) * 32;
    const int cb = (wave & 1) * 128;         // column half
    f32x16 acc[4];
#pragma unroll
    for (int nt = 0; nt < 4; ++nt)
#pragma unroll
        for (int i = 0; i < 16; ++i) acc[nt][i] = 0.f;
    f32x16 acce;
#pragma unroll
    for (int i = 0; i < 16; ++i) acce[i] = 0.f;
    int mrow = m0 + c; if (mrow >= N_NODES) mrow = N_NODES - 1;
    const size_t abase = (size_t)mrow * K + quad * 8;
    for (int k0 = 0; k0 < K; k0 += 16) {
        bf16x8 af = *(const bf16x8*)(A + abase + k0);
        const unsigned short* bk = Bp + ((size_t)(k0 >> 3) + quad) * (HC * 8);
#pragma unroll
        for (int nt = 0; nt < 4; ++nt) {
            bf16x8 bf = *(const bf16x8*)(bk + (cb + nt * 32 + c) * 8);
            acc[nt] = __builtin_amdgcn_mfma_f32_32x32x16_bf16(af, bf, acc[nt], 0, 0, 0);
        }
        if (wave & 1) {
            bf16x8 bfe = *(const bf16x8*)(Ext + ((k0 >> 3) + quad) * 256 + c * 8);
            acce = __builtin_amdgcn_mfma_f32_32x32x16_bf16(af, bfe, acce, 0, 0, 0);
        }
    }
#pragma unroll
    for (int reg = 0; reg < 16; ++reg) {
        int row = (reg & 3) + 8 * (reg >> 2) + 4 * quad;
        int m = m0 + row;
        if (m < N_NODES) {
            size_t base = (size_t)m * HC + cb + c;
#pragma unroll
            for (int nt = 0; nt < 4; ++nt)
                hh[base + nt * 32] = (unsigned short)bf16rne(acc[nt][reg]);
            if ((wave & 1) && c < 8) {
                float v = acce[reg];
                if (c < 4) a_src[m * HEADS + c] = v;
                else       a_dst[m * HEADS + (c - 4)] = v;
            }
        }
    }
}

// ================= CSR build (dst-sorted edge list) =================
__global__ void k_hist(const int* __restrict__ ei, int* __restrict__ counts,
                       int* __restrict__ rank) {
    int e = blockIdx.x * blockDim.x + threadIdx.x;
    if (e >= EP) return;
    int d = (e < N_EDGES) ? ei[N_EDGES + e] : (e - N_EDGES);
    rank[e] = atomicAdd(&counts[d], 1);
}

__global__ void k_scan1(const int* __restrict__ counts, int* __restrict__ chunk_excl,
                        int* __restrict__ bsum) {
    __shared__ int buf[SCAN_B];
    int i = blockIdx.x * SCAN_B + threadIdx.x;
    int v = (i < N_NODES) ? counts[i] : 0;
    buf[threadIdx.x] = v;
    __syncthreads();
    for (int off = 1; off < SCAN_B; off <<= 1) {
        int t = (threadIdx.x >= off) ? buf[threadIdx.x - off] : 0;
        __syncthreads();
        buf[threadIdx.x] += t;
        __syncthreads();
    }
    if (i < N_NODES) chunk_excl[i] = buf[threadIdx.x] - v;
    if (threadIdx.x == SCAN_B - 1) bsum[blockIdx.x] = buf[SCAN_B - 1];
}

__global__ void k_scan3(const int* __restrict__ chunk_excl, const int* __restrict__ bsum,
                        int* __restrict__ row_ptr) {
    __shared__ int sbase;
    if (threadIdx.x < 64) {
        int v = (threadIdx.x < blockIdx.x) ? bsum[threadIdx.x] : 0;   // NB=49 <= 64
#pragma unroll
        for (int mk = 1; mk < 64; mk <<= 1) v += __shfl_xor(v, mk, 64);
        if (threadIdx.x == 0) sbase = v;
    }
    __syncthreads();
    int i = blockIdx.x * SCAN_B + threadIdx.x;
    if (i < N_NODES) row_ptr[i] = chunk_excl[i] + sbase;
    if (i == 0) row_ptr[N_NODES] = EP;
}

__global__ void k_scatter(const int* __restrict__ ei, const int* __restrict__ row_ptr,
                          const int* __restrict__ rank, int* __restrict__ esrc) {
    int e = blockIdx.x * blockDim.x + threadIdx.x;
    if (e >= EP) return;
    int s, d;
    if (e < N_EDGES) { s = ei[e]; d = ei[N_EDGES + e]; } else { s = d = e - N_EDGES; }
    esrc[row_ptr[d] + rank[e]] = s;
}

// ===== fused GAT aggregate: HALF-wave per dst node, lane owns 8 cols (uint4) =====
__global__ __launch_bounds__(256) void k_gat_agg(
        const int* __restrict__ row_ptr, const int* __restrict__ esrc,
        const unsigned short* __restrict__ hh, const float* __restrict__ a_src,
        const float* __restrict__ a_dst, const float* __restrict__ bias,
        unsigned short* __restrict__ out) {
    const int wave = threadIdx.x >> 6;
    const int lane = threadIdx.x & 63;
    const int half = lane >> 5;
    const int l = lane & 31;
    const int d = blockIdx.x * 8 + wave * 2 + half;   // 50000 = 6250*8, exact
    const int h = l >> 3;
    const unsigned c0 = (unsigned)(l * 8);
    const int bsrc = half << 5;                        // shfl base lane
    const float ad = a_dst[((unsigned)d << 2) + h];
    const int beg = row_ptr[d], end = row_ptr[d + 1];
    float acc[8];
#pragma unroll
    for (int t = 0; t < 8; ++t) acc[t] = 0.f;
    float psum = 0.f;
    for (int base = beg; base < end; base += 32) {
        int cnt = end - base; if (cnt > 32) cnt = 32;
        int idx = base + l;
        int myv = esrc[idx < end ? idx : end - 1];
        int i = 0;
        for (; i + 4 <= cnt; i += 4) {
            int s0 = __shfl(myv, bsrc + i, 64);
            int s1 = __shfl(myv, bsrc + i + 1, 64);
            int s2 = __shfl(myv, bsrc + i + 2, 64);
            int s3 = __shfl(myv, bsrc + i + 3, 64);
            float as0 = a_src[((unsigned)s0 << 2) + h];
            float as1 = a_src[((unsigned)s1 << 2) + h];
            float as2 = a_src[((unsigned)s2 << 2) + h];
            float as3 = a_src[((unsigned)s3 << 2) + h];
            uint4 g0 = *(const uint4*)(hh + (((unsigned)s0 << 8) + c0));
            uint4 g1 = *(const uint4*)(hh + (((unsigned)s1 << 8) + c0));
            uint4 g2 = *(const uint4*)(hh + (((unsigned)s2 << 8) + c0));
            uint4 g3 = *(const uint4*)(hh + (((unsigned)s3 << 8) + c0));
            float e0 = as0 + ad, e1 = as1 + ad, e2 = as2 + ad, e3 = as3 + ad;
            e0 = fmaxf(e0, NEG_SLOPE * e0); e1 = fmaxf(e1, NEG_SLOPE * e1);
            e2 = fmaxf(e2, NEG_SLOPE * e2); e3 = fmaxf(e3, NEG_SLOPE * e3);
            float p0 = __expf(e0), p1 = __expf(e1), p2 = __expf(e2), p3 = __expf(e3);
            psum += (p0 + p1) + (p2 + p3);
            acc[0] += p0 * bf_lo(g0.x) + p1 * bf_lo(g1.x) + p2 * bf_lo(g2.x) + p3 * bf_lo(g3.x);
            acc[1] += p0 * bf_hi_raw(g0.x) + p1 * bf_hi_raw(g1.x) + p2 * bf_hi_raw(g2.x) + p3 * bf_hi_raw(g3.x);
            acc[2] += p0 * bf_lo(g0.y) + p1 * bf_lo(g1.y) + p2 * bf_lo(g2.y) + p3 * bf_lo(g3.y);
            acc[3] += p0 * bf_hi_raw(g0.y) + p1 * bf_hi_raw(g1.y) + p2 * bf_hi_raw(g2.y) + p3 * bf_hi_raw(g3.y);
            acc[4] += p0 * bf_lo(g0.z) + p1 * bf_lo(g1.z) + p2 * bf_lo(g2.z) + p3 * bf_lo(g3.z);
            acc[5] += p0 * bf_hi_raw(g0.z) + p1 * bf_hi_raw(g1.z) + p2 * bf_hi_raw(g2.z) + p3 * bf_hi_raw(g3.z);
            acc[6] += p0 * bf_lo(g0.w) + p1 * bf_lo(g1.w) + p2 * bf_lo(g2.w) + p3 * bf_lo(g3.w);
            acc[7] += p0 * bf_hi_raw(g0.w) + p1 * bf_hi_raw(g1.w) + p2 * bf_hi_raw(g2.w) + p3 * bf_hi_raw(g3.w);
        }
        for (; i < cnt; ++i) {
            int s0 = __shfl(myv, bsrc + i, 64);
            float as0 = a_src[((unsigned)s0 << 2) + h];
            uint4 g0 = *(const uint4*)(hh + (((unsigned)s0 << 8) + c0));
            float e0 = as0 + ad;
            e0 = fmaxf(e0, NEG_SLOPE * e0);
            float p0 = __expf(e0);
            psum += p0;
            acc[0] += p0 * bf_lo(g0.x); acc[1] += p0 * bf_hi_raw(g0.x);
            acc[2] += p0 * bf_lo(g0.y); acc[3] += p0 * bf_hi_raw(g0.y);
            acc[4] += p0 * bf_lo(g0.z); acc[5] += p0 * bf_hi_raw(g0.z);
            acc[6] += p0 * bf_lo(g0.w); acc[7] += p0 * bf_hi_raw(g0.w);
        }
    }
    const float inv = 1.f / (psum + 1e-16f);
    const float4 bb0 = *(const float4*)(bias + c0);
    const float4 bb1 = *(const float4*)(bias + c0 + 4);
    float v[8];
    v[0] = acc[0] * inv + bb0.x; v[1] = acc[1] * inv + bb0.y;
    v[2] = acc[2] * inv + bb0.z; v[3] = acc[3] * inv + bb0.w;
    v[4] = acc[4] * inv + bb1.x; v[5] = acc[5] * inv + bb1.y;
    v[6] = acc[6] * inv + bb1.z; v[7] = acc[7] * inv + bb1.w;
#pragma unroll
    for (int t = 0; t < 8; ++t) v[t] = v[t] > 0.f ? v[t] : (__expf(v[t]) - 1.f);
    uint4 pk;
    pk.x = pack_bf2(v[0], v[1]); pk.y = pack_bf2(v[2], v[3]);
    pk.z = pack_bf2(v[4], v[5]); pk.w = pack_bf2(v[6], v[7]);
    *(uint4*)(out + (((size_t)d << 8) + c0)) = pk;
}

// ======= MFMA out-proj + fused LayerNorm: out[M,128] = A[M,256] @ B -> LN =======
__global__ __launch_bounds__(256) void k_gemm_out(
        const unsigned short* __restrict__ A, const unsigned short* __restrict__ Bp,
        const float* __restrict__ b, const float* __restrict__ gamma,
        const float* __restrict__ beta, float* __restrict__ out) {
    const int lane = threadIdx.x & 63;
    const int quad = lane >> 5, c = lane & 31;
    const int m0 = blockIdx.x * 128 + (threadIdx.x >> 6) * 32;
    f32x16 acc[4];
#pragma unroll
    for (int nt = 0; nt < 4; ++nt)
#pragma unroll
        for (int i = 0; i < 16; ++i) acc[nt][i] = 0.f;
    int mrow = m0 + c; if (mrow >= N_NODES) mrow = N_NODES - 1;
    const size_t abase = (size_t)mrow * HC + quad * 8;
    for (int k0 = 0; k0 < HC; k0 += 16) {
        bf16x8 af = *(const bf16x8*)(A + abase + k0);
        const unsigned short* bk = Bp + ((size_t)(k0 >> 3) + quad) * (OUT_DIM * 8);
#pragma unroll
        for (int nt = 0; nt < 4; ++nt) {
            bf16x8 bf = *(const bf16x8*)(bk + (nt * 32 + c) * 8);
            acc[nt] = __builtin_amdgcn_mfma_f32_32x32x16_bf16(af, bf, acc[nt], 0, 0, 0);
        }
    }
    float bb[4], gg[4], be[4];
#pragma unroll
    for (int nt = 0; nt < 4; ++nt) {
        int col = nt * 32 + c;
        bb[nt] = b[col]; gg[nt] = gamma[col]; be[nt] = beta[col];
    }
#pragma unroll
    for (int reg = 0; reg < 16; ++reg) {
        int row = (reg & 3) + 8 * (reg >> 2) + 4 * quad;
        int m = m0 + row;
        float v[4];
        float s = 0.f, s2 = 0.f;
#pragma unroll
        for (int nt = 0; nt < 4; ++nt) {
            v[nt] = acc[nt][reg] + bb[nt];
            s += v[nt]; s2 += v[nt] * v[nt];
        }
#pragma unroll
        for (int mk = 1; mk < 32; mk <<= 1) {
            s += __shfl_xor(s, mk, 64);
            s2 += __shfl_xor(s2, mk, 64);
        }
        float mu = s * (1.f / OUT_DIM);
        float var = s2 * (1.f / OUT_DIM) - mu * mu;
        float inv = rsqrtf(var + LN_EPS);
        if (m < N_NODES) {
            size_t base = (size_t)m * OUT_DIM + c;
#pragma unroll
            for (int nt = 0; nt < 4; ++nt)
                out[base + nt * 32] = (v[nt] - mu) * inv * gg[nt] + be[nt];
        }
    }
}

extern "C" void kernel_launch(void* const* d_in, const int* in_sizes, int n_in,
                              void* d_out, int out_size, void* d_ws, size_t ws_size,
                              hipStream_t stream) {
    const float* x        = (const float*)d_in[0];
    const int*   ei       = (const int*)  d_in[1];
    const float* W_in     = (const float*)d_in[2];
    const float* b_in     = (const float*)d_in[3];
    const float* lin0_w   = (const float*)d_in[4];
    const float* att0_src = (const float*)d_in[5];
    const float* att0_dst = (const float*)d_in[6];
    const float* bias0    = (const float*)d_in[7];
    const float* lin1_w   = (const float*)d_in[8];
    const float* att1_src = (const float*)d_in[9];
    const float* att1_dst = (const float*)d_in[10];
    const float* bias1    = (const float*)d_in[11];
    const float* W_out    = (const float*)d_in[12];
    const float* b_out    = (const float*)d_in[13];
    const float* ln_gamma = (const float*)d_in[14];
    const float* ln_beta  = (const float*)d_in[15];
    float* out = (float*)d_out;

    unsigned short* us = (unsigned short*)d_ws;
    unsigned short* h_in_bf = us;                                  // N*HID
    unsigned short* hh_bf   = h_in_bf + (size_t)N_NODES * HID;     // N*HC
    unsigned short* feat_bf = hh_bf + (size_t)N_NODES * HC;        // N*HC
    unsigned short* p0      = feat_bf + (size_t)N_NODES * HC;      // 64*256
    unsigned short* p1      = p0 + HID * HC;                       // 256*256
    unsigned short* p2      = p1 + HC * HC;                        // 256*128
    unsigned short* ext0    = p2 + HC * OUT_DIM;                   // 2048
    unsigned short* ext1    = ext0 + 2048;                         // 8192
    float* a_src = (float*)(ext1 + 8192);
    float* a_dst = a_src + (size_t)N_NODES * HEADS;
    int* counts     = (int*)(a_dst + (size_t)N_NODES * HEADS);
    int* chunk_excl = counts + N_NODES;
    int* bsum       = chunk_excl + N_NODES;
    int* row_ptr    = bsum + NB;
    int* rank       = row_ptr + N_NODES + 1;       // EP
    int* esrc       = rank + EP;                   // EP

    // 1. fused prep: input proj + weight packing + combined att columns
    k_prep<<<PREP_INPROJ + PREP_WPACK + PREP_EXT, 256, 0, stream>>>(
        x, W_in, b_in, h_in_bf, lin0_w, lin1_w, W_out, p0, p1, p2,
        att0_src, att0_dst, ext0, att1_src, att1_dst, ext1);

    // 2. CSR build (once; shared by both GAT layers)
    hipMemsetAsync(counts, 0, N_NODES * sizeof(int), stream);
    k_hist<<<(EP + 255) / 256, 256, 0, stream>>>(ei, counts, rank);
    k_scan1<<<NB, SCAN_B, 0, stream>>>(counts, chunk_excl, bsum);
    k_scan3<<<NB, SCAN_B, 0, stream>>>(chunk_excl, bsum, row_ptr);
    k_scatter<<<(EP + 255) / 256, 256, 0, stream>>>(ei, row_ptr, rank, esrc);

    const int lin_grid = (N_NODES + 63) / 64;      // 782
    const int out_grid = (N_NODES + 127) / 128;    // 391

    // ---- GAT layer 0 ----
    k_gemm_lin<HID><<<lin_grid, 256, 0, stream>>>(h_in_bf, p0, ext0, hh_bf, a_src, a_dst);
    k_gat_agg<<<N_NODES / 8, 256, 0, stream>>>(row_ptr, esrc, hh_bf, a_src, a_dst,
                                               bias0, feat_bf);

    // ---- GAT layer 1 ----
    k_gemm_lin<HC><<<lin_grid, 256, 0, stream>>>(feat_bf, p1, ext1, hh_bf, a_src, a_dst);
    k_gat_agg<<<N_NODES / 8, 256, 0, stream>>>(row_ptr, esrc, hh_bf, a_src, a_dst,
                                               bias1, feat_bf);

    // ---- output projection + LayerNorm ----
    k_gemm_out<<<out_grid, 256, 0, stream>>>(feat_bf, p2, b_out, ln_gamma, ln_beta, out);
}

// Round 10
// 357.747 us; speedup vs baseline: 1.3244x; 1.0202x over previous
//
#include <hip/hip_runtime.h>
#include <cstdint>

#define N_NODES 50000
#define N_EDGES 800000
#define EP (N_EDGES + N_NODES)   // edges + self-loops
#define IN_DIM 32
#define HID 64
#define HEADS 4
#define HC 256                   // HID*HEADS
#define OUT_DIM 128
#define NEG_SLOPE 0.2f
#define LN_EPS 1e-5f
#define SCAN_B 1024
#define NB ((N_NODES + SCAN_B - 1) / SCAN_B)   // 49

typedef __attribute__((ext_vector_type(8))) short bf16x8;
typedef __attribute__((ext_vector_type(16))) float f32x16;

__device__ __forceinline__ unsigned bf16rne(float f) {
    unsigned u = __float_as_uint(f);
    return (u + 0x7fffu + ((u >> 16) & 1u)) >> 16;
}
__device__ __forceinline__ unsigned pack_bf2(float a, float b) {
    return bf16rne(a) | (bf16rne(b) << 16);
}
__device__ __forceinline__ float bf_lo(unsigned w) { return __uint_as_float(w << 16); }
// hi half used raw: low 16 bits are sub-ulp noise (< 1 bf16 ulp), skip the AND
__device__ __forceinline__ float bf_hi_raw(unsigned w) { return __uint_as_float(w); }

// ===== fused prep: in_proj | weight pack | att-ext columns | edge histogram =====
#define PREP_INPROJ ((N_NODES * HID) / 256)                    // 12500
#define PREP_WPACK ((HID * HC + HC * HC + HC * OUT_DIM) / 256) // 448
#define PREP_EXT 40                                            // 2048+8192 elems
#define PREP_HIST ((EP + 255) / 256)                           // 3321
__global__ void k_prep(const float* __restrict__ x, const float* __restrict__ W_in,
                       const float* __restrict__ b_in, unsigned short* __restrict__ h_in,
                       const float* __restrict__ w0, const float* __restrict__ w1,
                       const float* __restrict__ w2, unsigned short* __restrict__ p0,
                       unsigned short* __restrict__ p1, unsigned short* __restrict__ p2,
                       const float* __restrict__ as0, const float* __restrict__ ad0,
                       unsigned short* __restrict__ ext0,
                       const float* __restrict__ as1, const float* __restrict__ ad1,
                       unsigned short* __restrict__ ext1,
                       const int* __restrict__ ei, int* __restrict__ counts,
                       int* __restrict__ rank) {
    if (blockIdx.x < PREP_INPROJ) {
        int g = blockIdx.x * 256 + threadIdx.x;
        int n = g >> 6, j = g & 63;
        const float* xr = x + n * IN_DIM;
        float acc = b_in[j];
#pragma unroll
        for (int k = 0; k < IN_DIM; ++k) acc += xr[k] * W_in[k * HID + j];
        acc = acc > 0.f ? acc : (__expf(acc) - 1.f);
        h_in[g] = (unsigned short)bf16rne(acc);
    } else if (blockIdx.x < PREP_INPROJ + PREP_WPACK) {
        int g = (blockIdx.x - PREP_INPROJ) * 256 + threadIdx.x;
        if (g < HID * HC) {                      // lin0_w: 64x256
            int k = g >> 8, n = g & 255;
            p0[(((k >> 3) * HC) + n) * 8 + (k & 7)] = (unsigned short)bf16rne(w0[g]);
        } else if (g < HID * HC + HC * HC) {     // lin1_w: 256x256
            int t = g - HID * HC;
            int k = t >> 8, n = t & 255;
            p1[(((k >> 3) * HC) + n) * 8 + (k & 7)] = (unsigned short)bf16rne(w1[t]);
        } else {                                 // W_out: 256x128
            int t = g - HID * HC - HC * HC;
            int k = t >> 7, n = t & 127;
            p2[(((k >> 3) * OUT_DIM) + n) * 8 + (k & 7)] = (unsigned short)bf16rne(w2[t]);
        }
    } else if (blockIdx.x < PREP_INPROJ + PREP_WPACK + PREP_EXT) {
        int t = (blockIdx.x - PREP_INPROJ - PREP_WPACK) * 256 + threadIdx.x;
        const float* w; const float* as; const float* ad; unsigned short* ext; int e;
        if (t < 2048) { w = w0; as = as0; ad = ad0; ext = ext0; e = t; }
        else if (t < 2048 + 8192) { w = w1; as = as1; ad = ad1; ext = ext1; e = t - 2048; }
        else return;
        int kb = e >> 8, rem = e & 255, col = rem >> 3, kk = rem & 7;
        int k = kb * 8 + kk;
        float acc = 0.f;
        if (col < 8) {
            int h = col & 3;
            const float* att = (col < 4) ? as : ad;
#pragma unroll 4
            for (int c = 0; c < HID; ++c) acc += w[k * HC + h * HID + c] * att[h * HID + c];
        }
        ext[e] = (unsigned short)bf16rne(acc);
    } else {
        int e = (blockIdx.x - PREP_INPROJ - PREP_WPACK - PREP_EXT) * 256 + threadIdx.x;
        if (e >= EP) return;
        int d = (e < N_EDGES) ? ei[N_EDGES + e] : (e - N_EDGES);
        rank[e] = atomicAdd(&counts[d], 1);
    }
}

// ===== single-launch scan: 49 co-resident blocks + device-scope release spin =====
__global__ void k_scan(const int* __restrict__ counts, int* __restrict__ bsum,
                       int* __restrict__ done, int* __restrict__ row_ptr) {
    __shared__ int buf[SCAN_B];
    __shared__ int sbase;
    int i = blockIdx.x * SCAN_B + threadIdx.x;
    int v = (i < N_NODES) ? counts[i] : 0;
    buf[threadIdx.x] = v;
    __syncthreads();
    for (int off = 1; off < SCAN_B; off <<= 1) {
        int t = (threadIdx.x >= off) ? buf[threadIdx.x - off] : 0;
        __syncthreads();
        buf[threadIdx.x] += t;
        __syncthreads();
    }
    int excl = buf[threadIdx.x] - v;
    if (threadIdx.x == SCAN_B - 1) {
        bsum[blockIdx.x] = buf[SCAN_B - 1];
        __threadfence();                        // make bsum visible device-wide
        atomicAdd(done, 1);
    }
    if (threadIdx.x == 0) {
        while (__hip_atomic_load(done, __ATOMIC_RELAXED, __HIP_MEMORY_SCOPE_AGENT) < NB) {
            __builtin_amdgcn_s_sleep(8);
        }
    }
    __syncthreads();
    if (threadIdx.x < 64) {
        int t = threadIdx.x;
        int val = (t < blockIdx.x)
                ? __hip_atomic_load(&bsum[t], __ATOMIC_RELAXED, __HIP_MEMORY_SCOPE_AGENT) : 0;
#pragma unroll
        for (int mk = 1; mk < 64; mk <<= 1) val += __shfl_xor(val, mk, 64);
        if (t == 0) sbase = val;
    }
    __syncthreads();
    if (i < N_NODES) row_ptr[i] = excl + sbase;
    if (i == 0) row_ptr[N_NODES] = EP;
}

// ======= MFMA GEMM body: hh[M,256] = A[M,K] @ B[K,256]; odd waves also do =======
// ======= the 8 attention-dot columns (extra B-tile) -> a_src/a_dst directly =====
template <int K>
__device__ __forceinline__ void gemm_lin_body(
        int mblk, const unsigned short* __restrict__ A, const unsigned short* __restrict__ Bp,
        const unsigned short* __restrict__ Ext, unsigned short* __restrict__ hh,
        float* __restrict__ a_src, float* __restrict__ a_dst) {
    const int lane = threadIdx.x & 63;
    const int quad = lane >> 5, c = lane & 31;
    const int wave = threadIdx.x >> 6;
    const int m0 = mblk * 64 + (wave >> 1) * 32;
    const int cb = (wave & 1) * 128;         // column half
    f32x16 acc[4];
#pragma unroll
    for (int nt = 0; nt < 4; ++nt)
#pragma unroll
        for (int i = 0; i < 16; ++i) acc[nt][i] = 0.f;
    f32x16 acce;
#pragma unroll
    for (int i = 0; i < 16; ++i) acce[i] = 0.f;
    int mrow = m0 + c; if (mrow >= N_NODES) mrow = N_NODES - 1;
    const size_t abase = (size_t)mrow * K + quad * 8;
    for (int k0 = 0; k0 < K; k0 += 16) {
        bf16x8 af = *(const bf16x8*)(A + abase + k0);
        const unsigned short* bk = Bp + ((size_t)(k0 >> 3) + quad) * (HC * 8);
#pragma unroll
        for (int nt = 0; nt < 4; ++nt) {
            bf16x8 bf = *(const bf16x8*)(bk + (cb + nt * 32 + c) * 8);
            acc[nt] = __builtin_amdgcn_mfma_f32_32x32x16_bf16(af, bf, acc[nt], 0, 0, 0);
        }
        if (wave & 1) {
            bf16x8 bfe = *(const bf16x8*)(Ext + ((k0 >> 3) + quad) * 256 + c * 8);
            acce = __builtin_amdgcn_mfma_f32_32x32x16_bf16(af, bfe, acce, 0, 0, 0);
        }
    }
#pragma unroll
    for (int reg = 0; reg < 16; ++reg) {
        int row = (reg & 3) + 8 * (reg >> 2) + 4 * quad;
        int m = m0 + row;
        if (m < N_NODES) {
            size_t base = (size_t)m * HC + cb + c;
#pragma unroll
            for (int nt = 0; nt < 4; ++nt)
                hh[base + nt * 32] = (unsigned short)bf16rne(acc[nt][reg]);
            if ((wave & 1) && c < 8) {
                float v = acce[reg];
                if (c < 4) a_src[m * HEADS + c] = v;
                else       a_dst[m * HEADS + (c - 4)] = v;
            }
        }
    }
}

template <int K>
__global__ __launch_bounds__(256) void k_gemm_lin(
        const unsigned short* __restrict__ A, const unsigned short* __restrict__ Bp,
        const unsigned short* __restrict__ Ext, unsigned short* __restrict__ hh,
        float* __restrict__ a_src, float* __restrict__ a_dst) {
    gemm_lin_body<K>(blockIdx.x, A, Bp, Ext, hh, a_src, a_dst);
}

// ======= layer-0 GEMM fused with CSR scatter (independent block ranges) =======
#define G0_BLOCKS ((N_NODES + 63) / 64)   // 782
__global__ __launch_bounds__(256) void k_gemm0_scatter(
        const unsigned short* __restrict__ A, const unsigned short* __restrict__ Bp,
        const unsigned short* __restrict__ Ext, unsigned short* __restrict__ hh,
        float* __restrict__ a_src, float* __restrict__ a_dst,
        const int* __restrict__ ei, const int* __restrict__ row_ptr,
        const int* __restrict__ rank, int* __restrict__ esrc) {
    if (blockIdx.x < G0_BLOCKS) {
        gemm_lin_body<HID>(blockIdx.x, A, Bp, Ext, hh, a_src, a_dst);
        return;
    }
    int e = (blockIdx.x - G0_BLOCKS) * 256 + threadIdx.x;
    if (e < EP) {
        int s, d;
        if (e < N_EDGES) { s = ei[e]; d = ei[N_EDGES + e]; } else { s = d = e - N_EDGES; }
        esrc[row_ptr[d] + rank[e]] = s;
    } else if (e - EP < 64) {
        esrc[e] = 0;                     // pad tail so agg chunk loads need no clamp
    }
}

// ===== fused GAT aggregate: HALF-wave per dst node, lane owns 8 cols (uint4) =====
__global__ __launch_bounds__(256) void k_gat_agg(
        const int* __restrict__ row_ptr, const int* __restrict__ esrc,
        const unsigned short* __restrict__ hh, const float* __restrict__ a_src,
        const float* __restrict__ a_dst, const float* __restrict__ bias,
        unsigned short* __restrict__ out) {
    const int wave = threadIdx.x >> 6;
    const int lane = threadIdx.x & 63;
    const int half = lane >> 5;
    const int l = lane & 31;
    const int d = blockIdx.x * 8 + wave * 2 + half;   // 50000 = 6250*8, exact
    const int h = l >> 3;
    const unsigned c0 = (unsigned)(l * 8);
    const int bsrc = half << 5;                        // shfl base lane
    const float ad = a_dst[((unsigned)d << 2) + h];
    const int beg = row_ptr[d], end = row_ptr[d + 1];
    float acc[8];
#pragma unroll
    for (int t = 0; t < 8; ++t) acc[t] = 0.f;
    float psum = 0.f;
    int myv = esrc[beg + l];                           // pad-safe, no clamp
    for (int base = beg; base < end; base += 32) {
        int rem = end - base;
        int cnt = rem > 32 ? 32 : rem;
        int nxt = 0;
        if (rem > 32) nxt = esrc[base + 32 + l];       // prefetch next chunk
        int i = 0;
        for (; i + 4 <= cnt; i += 4) {
            int s0 = __shfl(myv, bsrc + i, 64);
            int s1 = __shfl(myv, bsrc + i + 1, 64);
            int s2 = __shfl(myv, bsrc + i + 2, 64);
            int s3 = __shfl(myv, bsrc + i + 3, 64);
            float as0 = a_src[((unsigned)s0 << 2) + h];
            float as1 = a_src[((unsigned)s1 << 2) + h];
            float as2 = a_src[((unsigned)s2 << 2) + h];
            float as3 = a_src[((unsigned)s3 << 2) + h];
            uint4 g0 = *(const uint4*)(hh + (((unsigned)s0 << 8) + c0));
            uint4 g1 = *(const uint4*)(hh + (((unsigned)s1 << 8) + c0));
            uint4 g2 = *(const uint4*)(hh + (((unsigned)s2 << 8) + c0));
            uint4 g3 = *(const uint4*)(hh + (((unsigned)s3 << 8) + c0));
            float e0 = as0 + ad, e1 = as1 + ad, e2 = as2 + ad, e3 = as3 + ad;
            e0 = fmaxf(e0, NEG_SLOPE * e0); e1 = fmaxf(e1, NEG_SLOPE * e1);
            e2 = fmaxf(e2, NEG_SLOPE * e2); e3 = fmaxf(e3, NEG_SLOPE * e3);
            float p0 = __expf(e0), p1 = __expf(e1), p2 = __expf(e2), p3 = __expf(e3);
            psum += (p0 + p1) + (p2 + p3);
            acc[0] += p0 * bf_lo(g0.x) + p1 * bf_lo(g1.x) + p2 * bf_lo(g2.x) + p3 * bf_lo(g3.x);
            acc[1] += p0 * bf_hi_raw(g0.x) + p1 * bf_hi_raw(g1.x) + p2 * bf_hi_raw(g2.x) + p3 * bf_hi_raw(g3.x);
            acc[2] += p0 * bf_lo(g0.y) + p1 * bf_lo(g1.y) + p2 * bf_lo(g2.y) + p3 * bf_lo(g3.y);
            acc[3] += p0 * bf_hi_raw(g0.y) + p1 * bf_hi_raw(g1.y) + p2 * bf_hi_raw(g2.y) + p3 * bf_hi_raw(g3.y);
            acc[4] += p0 * bf_lo(g0.z) + p1 * bf_lo(g1.z) + p2 * bf_lo(g2.z) + p3 * bf_lo(g3.z);
            acc[5] += p0 * bf_hi_raw(g0.z) + p1 * bf_hi_raw(g1.z) + p2 * bf_hi_raw(g2.z) + p3 * bf_hi_raw(g3.z);
            acc[6] += p0 * bf_lo(g0.w) + p1 * bf_lo(g1.w) + p2 * bf_lo(g2.w) + p3 * bf_lo(g3.w);
            acc[7] += p0 * bf_hi_raw(g0.w) + p1 * bf_hi_raw(g1.w) + p2 * bf_hi_raw(g2.w) + p3 * bf_hi_raw(g3.w);
        }
        for (; i < cnt; ++i) {
            int s0 = __shfl(myv, bsrc + i, 64);
            float as0 = a_src[((unsigned)s0 << 2) + h];
            uint4 g0 = *(const uint4*)(hh + (((unsigned)s0 << 8) + c0));
            float e0 = as0 + ad;
            e0 = fmaxf(e0, NEG_SLOPE * e0);
            float p0 = __expf(e0);
            psum += p0;
            acc[0] += p0 * bf_lo(g0.x); acc[1] += p0 * bf_hi_raw(g0.x);
            acc[2] += p0 * bf_lo(g0.y); acc[3] += p0 * bf_hi_raw(g0.y);
            acc[4] += p0 * bf_lo(g0.z); acc[5] += p0 * bf_hi_raw(g0.z);
            acc[6] += p0 * bf_lo(g0.w); acc[7] += p0 * bf_hi_raw(g0.w);
        }
        myv = nxt;
    }
    const float inv = 1.f / (psum + 1e-16f);
    const float4 bb0 = *(const float4*)(bias + c0);
    const float4 bb1 = *(const float4*)(bias + c0 + 4);
    float v[8];
    v[0] = acc[0] * inv + bb0.x; v[1] = acc[1] * inv + bb0.y;
    v[2] = acc[2] * inv + bb0.z; v[3] = acc[3] * inv + bb0.w;
    v[4] = acc[4] * inv + bb1.x; v[5] = acc[5] * inv + bb1.y;
    v[6] = acc[6] * inv + bb1.z; v[7] = acc[7] * inv + bb1.w;
#pragma unroll
    for (int t = 0; t < 8; ++t) v[t] = v[t] > 0.f ? v[t] : (__expf(v[t]) - 1.f);
    uint4 pk;
    pk.x = pack_bf2(v[0], v[1]); pk.y = pack_bf2(v[2], v[3]);
    pk.z = pack_bf2(v[4], v[5]); pk.w = pack_bf2(v[6], v[7]);
    *(uint4*)(out + (((size_t)d << 8) + c0)) = pk;
}

// ======= MFMA out-proj + fused LayerNorm: out[M,128] = A[M,256] @ B -> LN =======
__global__ __launch_bounds__(256) void k_gemm_out(
        const unsigned short* __restrict__ A, const unsigned short* __restrict__ Bp,
        const float* __restrict__ b, const float* __restrict__ gamma,
        const float* __restrict__ beta, float* __restrict__ out) {
    const int lane = threadIdx.x & 63;
    const int quad = lane >> 5, c = lane & 31;
    const int m0 = blockIdx.x * 128 + (threadIdx.x >> 6) * 32;
    f32x16 acc[4];
#pragma unroll
    for (int nt = 0; nt < 4; ++nt)
#pragma unroll
        for (int i = 0; i < 16; ++i) acc[nt][i] = 0.f;
    int mrow = m0 + c; if (mrow >= N_NODES) mrow = N_NODES - 1;
    const size_t abase = (size_t)mrow * HC + quad * 8;
    for (int k0 = 0; k0 < HC; k0 += 16) {
        bf16x8 af = *(const bf16x8*)(A + abase + k0);
        const unsigned short* bk = Bp + ((size_t)(k0 >> 3) + quad) * (OUT_DIM * 8);
#pragma unroll
        for (int nt = 0; nt < 4; ++nt) {
            bf16x8 bf = *(const bf16x8*)(bk + (nt * 32 + c) * 8);
            acc[nt] = __builtin_amdgcn_mfma_f32_32x32x16_bf16(af, bf, acc[nt], 0, 0, 0);
        }
    }
    float bb[4], gg[4], be[4];
#pragma unroll
    for (int nt = 0; nt < 4; ++nt) {
        int col = nt * 32 + c;
        bb[nt] = b[col]; gg[nt] = gamma[col]; be[nt] = beta[col];
    }
#pragma unroll
    for (int reg = 0; reg < 16; ++reg) {
        int row = (reg & 3) + 8 * (reg >> 2) + 4 * quad;
        int m = m0 + row;
        float v[4];
        float s = 0.f, s2 = 0.f;
#pragma unroll
        for (int nt = 0; nt < 4; ++nt) {
            v[nt] = acc[nt][reg] + bb[nt];
            s += v[nt]; s2 += v[nt] * v[nt];
        }
#pragma unroll
        for (int mk = 1; mk < 32; mk <<= 1) {
            s += __shfl_xor(s, mk, 64);
            s2 += __shfl_xor(s2, mk, 64);
        }
        float mu = s * (1.f / OUT_DIM);
        float var = s2 * (1.f / OUT_DIM) - mu * mu;
        float inv = rsqrtf(var + LN_EPS);
        if (m < N_NODES) {
            size_t base = (size_t)m * OUT_DIM + c;
#pragma unroll
            for (int nt = 0; nt < 4; ++nt)
                out[base + nt * 32] = (v[nt] - mu) * inv * gg[nt] + be[nt];
        }
    }
}

extern "C" void kernel_launch(void* const* d_in, const int* in_sizes, int n_in,
                              void* d_out, int out_size, void* d_ws, size_t ws_size,
                              hipStream_t stream) {
    const float* x        = (const float*)d_in[0];
    const int*   ei       = (const int*)  d_in[1];
    const float* W_in     = (const float*)d_in[2];
    const float* b_in     = (const float*)d_in[3];
    const float* lin0_w   = (const float*)d_in[4];
    const float* att0_src = (const float*)d_in[5];
    const float* att0_dst = (const float*)d_in[6];
    const float* bias0    = (const float*)d_in[7];
    const float* lin1_w   = (const float*)d_in[8];
    const float* att1_src = (const float*)d_in[9];
    const float* att1_dst = (const float*)d_in[10];
    const float* bias1    = (const float*)d_in[11];
    const float* W_out    = (const float*)d_in[12];
    const float* b_out    = (const float*)d_in[13];
    const float* ln_gamma = (const float*)d_in[14];
    const float* ln_beta  = (const float*)d_in[15];
    float* out = (float*)d_out;

    unsigned short* us = (unsigned short*)d_ws;
    unsigned short* h_in_bf = us;                                  // N*HID
    unsigned short* hh_bf   = h_in_bf + (size_t)N_NODES * HID;     // N*HC
    unsigned short* feat_bf = hh_bf + (size_t)N_NODES * HC;        // N*HC
    unsigned short* p0      = feat_bf + (size_t)N_NODES * HC;      // 64*256
    unsigned short* p1      = p0 + HID * HC;                       // 256*256
    unsigned short* p2      = p1 + HC * HC;                        // 256*128
    unsigned short* ext0    = p2 + HC * OUT_DIM;                   // 2048
    unsigned short* ext1    = ext0 + 2048;                         // 8192
    float* a_src = (float*)(ext1 + 8192);
    float* a_dst = a_src + (size_t)N_NODES * HEADS;
    int* counts  = (int*)(a_dst + (size_t)N_NODES * HEADS);        // N
    int* done    = counts + N_NODES;                               // 1 (zeroed w/ counts)
    int* bsum    = done + 1;                                       // NB
    int* row_ptr = bsum + NB;                                      // N+1
    int* rank    = row_ptr + N_NODES + 1;                          // EP
    int* esrc    = rank + EP;                                      // EP + 64 (padded)

    // 0. zero counts + done flag
    hipMemsetAsync(counts, 0, (N_NODES + 1) * sizeof(int), stream);

    // 1. fused prep: input proj + weight packing + att columns + edge histogram
    k_prep<<<PREP_INPROJ + PREP_WPACK + PREP_EXT + PREP_HIST, 256, 0, stream>>>(
        x, W_in, b_in, h_in_bf, lin0_w, lin1_w, W_out, p0, p1, p2,
        att0_src, att0_dst, ext0, att1_src, att1_dst, ext1, ei, counts, rank);

    // 2. single-launch scan -> row_ptr
    k_scan<<<NB, SCAN_B, 0, stream>>>(counts, bsum, done, row_ptr);

    // 3. layer-0 GEMM fused with CSR scatter
    k_gemm0_scatter<<<G0_BLOCKS + PREP_HIST, 256, 0, stream>>>(
        h_in_bf, p0, ext0, hh_bf, a_src, a_dst, ei, row_ptr, rank, esrc);
    k_gat_agg<<<N_NODES / 8, 256, 0, stream>>>(row_ptr, esrc, hh_bf, a_src, a_dst,
                                               bias0, feat_bf);

    // ---- GAT layer 1 ----
    k_gemm_lin<HC><<<(N_NODES + 63) / 64, 256, 0, stream>>>(feat_bf, p1, ext1, hh_bf,
                                                            a_src, a_dst);
    k_gat_agg<<<N_NODES / 8, 256, 0, stream>>>(row_ptr, esrc, hh_bf, a_src, a_dst,
                                               bias1, feat_bf);

    // ---- output projection + LayerNorm ----
    k_gemm_out<<<(N_NODES + 127) / 128, 256, 0, stream>>>(feat_bf, p2, b_out,
                                                          ln_gamma, ln_beta, out);
}